// Round 1
// baseline (895.799 us; speedup 1.0000x reference)
//
#include <hip/hip_runtime.h>
#include <hip/hip_bf16.h>

// ---------------------------------------------------------------------------
// SCFA fused pipeline, fp32 compute, bf16 bulk intermediates.
// B=8, C=256, H=W=64 (N=4096), NH=4, HD=64, 3C=768.
//
// ws layout (bytes):
//   0        weff[256*49] fp32 (fused 7x7 depthwise weights, /3 folded)
//   51200    beff[256]
//   53248    alpha[2][768]   (BN scale, qkv bias folded)
//   59392    beta [2][768]
//   65536    invq[2][2048]   (1/max(||q_row||,1e-12))
//   81920    invk[2][2048]
//   98304    pool[2][2048]   (SE sum-pool accumulators, memset to 0)
//   114688   gate[2][2048]
//   1048576  attn1[8*4*64*64] fp32
//   1572864  attn2
//   2097152  Spart[8*4*16*64*64] fp32 (16 n-chunk partial qk^T, reused per stream)
//   10485760 xf[8*256*4096] fp32 (multi-scale out; later reused for xout1/xout2 bf16)
//   44040192 qkv1[8*768*4096] bf16
//   94371840 qkv2[8*768*4096] bf16
//   total 144703488 (~138 MiB)
// ---------------------------------------------------------------------------

#define NPIX 4096

__device__ __forceinline__ float bf2f(unsigned short h) {
  return __uint_as_float(((unsigned)h) << 16);
}
__device__ __forceinline__ unsigned short f2bf(float f) {
  unsigned u = __float_as_uint(f);
  unsigned r = (u + 0x7FFFu + ((u >> 16) & 1u)) >> 16;
  return (unsigned short)r;
}
__device__ __forceinline__ float gelu_f(float x) {
  return 0.5f * x * (1.0f + erff(x * 0.70710678118654752440f));
}

// ---- prep: fold 3/5/7 depthwise kernels into one 7x7; fold BN+bias ----------
__global__ __launch_bounds__(256) void prep_kernel(
    const float* __restrict__ w3, const float* __restrict__ b3,
    const float* __restrict__ w5, const float* __restrict__ b5,
    const float* __restrict__ w7, const float* __restrict__ b7,
    const float* __restrict__ qb1, const float* __restrict__ g1,
    const float* __restrict__ be1, const float* __restrict__ m1,
    const float* __restrict__ v1,
    const float* __restrict__ qb2, const float* __restrict__ g2,
    const float* __restrict__ be2, const float* __restrict__ m2,
    const float* __restrict__ v2,
    float* __restrict__ weff, float* __restrict__ beff,
    float* __restrict__ alpha, float* __restrict__ beta)
{
  const int c = threadIdx.x;  // 256 threads
  for (int ky = 0; ky < 7; ++ky)
    for (int kx = 0; kx < 7; ++kx) {
      float w = w7[c * 49 + ky * 7 + kx];
      if (ky >= 1 && ky <= 5 && kx >= 1 && kx <= 5)
        w += w5[c * 25 + (ky - 1) * 5 + (kx - 1)];
      if (ky >= 2 && ky <= 4 && kx >= 2 && kx <= 4)
        w += w3[c * 9 + (ky - 2) * 3 + (kx - 2)];
      weff[c * 49 + ky * 7 + kx] = w * (1.0f / 3.0f);
    }
  beff[c] = (b3[c] + b5[c] + b7[c]) * (1.0f / 3.0f);
  for (int o = c; o < 768; o += 256) {
    float inv1 = g1[o] / sqrtf(v1[o] + 1e-5f);
    alpha[o] = inv1;
    beta[o]  = qb1[o] * inv1 + be1[o] - m1[o] * inv1;
    float inv2 = g2[o] / sqrtf(v2[o] + 1e-5f);
    alpha[768 + o] = inv2;
    beta[768 + o]  = qb2[o] * inv2 + be2[o] - m2[o] * inv2;
  }
}

// ---- fused multi-scale depthwise conv (single effective 7x7, SAME pad) ------
__global__ __launch_bounds__(256) void ms_conv(
    const float* __restrict__ x, const float* __restrict__ weff,
    const float* __restrict__ beff, float* __restrict__ xf)
{
  __shared__ float tile[70 * 70];
  __shared__ float wsh[49];
  __shared__ float bsh;
  const int bc = blockIdx.x;      // b*256 + c
  const int c = bc & 255;
  const int tid = threadIdx.x;
  const float* src = x + (size_t)bc * NPIX;
  if (tid < 49) wsh[tid] = weff[c * 49 + tid];
  if (tid == 63) bsh = beff[c];
  for (int idx = tid; idx < 4900; idx += 256) {
    int yy = idx / 70, xx = idx - yy * 70;
    int gy = yy - 3, gx = xx - 3;
    float v = 0.0f;
    if ((unsigned)gy < 64u && (unsigned)gx < 64u) v = src[gy * 64 + gx];
    tile[idx] = v;
  }
  __syncthreads();
  const int tx = tid & 63;
  const int y0 = (tid >> 6) * 16;   // 4 row-groups of 16
  float win[7][7];
#pragma unroll
  for (int r = 0; r < 6; ++r)
#pragma unroll
    for (int k = 0; k < 7; ++k) win[r][k] = tile[(y0 + r) * 70 + tx + k];
  float* dst = xf + (size_t)bc * NPIX;
#pragma unroll
  for (int i = 0; i < 16; ++i) {
#pragma unroll
    for (int k = 0; k < 7; ++k)
      win[(i + 6) % 7][k] = tile[(y0 + i + 6) * 70 + tx + k];
    float s = bsh;
#pragma unroll
    for (int r = 0; r < 7; ++r)
#pragma unroll
      for (int k = 0; k < 7; ++k)
        s = fmaf(wsh[r * 7 + k], win[(i + r) % 7][k], s);
    dst[(y0 + i) * 64 + tx] = s;
  }
}

// ---- qkv 1x1 conv GEMM + BN + gelu -> bf16 ---------------------------------
// grid (32, 6, 8): 128n x 128o tiles, K=256. 8x8 per thread fp32.
__global__ __launch_bounds__(256) void qkv_gemm(
    const float* __restrict__ xf, const float* __restrict__ W,
    const float* __restrict__ alpha, const float* __restrict__ beta,
    unsigned short* __restrict__ qkv)
{
  const int n0 = blockIdx.x * 128;
  const int o0 = blockIdx.y * 128;
  const int b  = blockIdx.z;
  const int tid = threadIdx.x;
  const int ti = tid >> 4, tj = tid & 15;
  __shared__ float As[8][132];
  __shared__ float Bs[8][132];
  float acc[8][8] = {};
  const float* xfb = xf + (size_t)b * 256 * NPIX;
  const int arow = tid >> 1, acol = (tid & 1) * 4;
  const int brow = tid >> 5, bcol = (tid & 31) * 4;
  for (int kc = 0; kc < 256; kc += 8) {
    float4 av4 = *(const float4*)&W[(size_t)(o0 + arow) * 256 + kc + acol];
    float4 bv4 = *(const float4*)&xfb[(size_t)(kc + brow) * NPIX + n0 + bcol];
    __syncthreads();
    As[acol + 0][arow] = av4.x; As[acol + 1][arow] = av4.y;
    As[acol + 2][arow] = av4.z; As[acol + 3][arow] = av4.w;
    *(float4*)&Bs[brow][bcol] = bv4;
    __syncthreads();
#pragma unroll
    for (int kk = 0; kk < 8; ++kk) {
      float a[8], bb[8];
      *(float4*)&a[0] = *(const float4*)&As[kk][ti * 8];
      *(float4*)&a[4] = *(const float4*)&As[kk][ti * 8 + 4];
      *(float4*)&bb[0] = *(const float4*)&Bs[kk][tj * 4];
      *(float4*)&bb[4] = *(const float4*)&Bs[kk][64 + tj * 4];
#pragma unroll
      for (int i = 0; i < 8; ++i)
#pragma unroll
        for (int j = 0; j < 8; ++j)
          acc[i][j] = fmaf(a[i], bb[j], acc[i][j]);
    }
  }
#pragma unroll
  for (int i = 0; i < 8; ++i) {
    const int o = o0 + ti * 8 + i;
    const float al = alpha[o], be = beta[o];
    unsigned short* dst = qkv + ((size_t)b * 768 + o) * NPIX + n0;
#pragma unroll
    for (int g = 0; g < 2; ++g) {
      float v0 = gelu_f(acc[i][g * 4 + 0] * al + be);
      float v1 = gelu_f(acc[i][g * 4 + 1] * al + be);
      float v2 = gelu_f(acc[i][g * 4 + 2] * al + be);
      float v3 = gelu_f(acc[i][g * 4 + 3] * al + be);
      uint2 pk;
      pk.x = (unsigned)f2bf(v0) | ((unsigned)f2bf(v1) << 16);
      pk.y = (unsigned)f2bf(v2) | ((unsigned)f2bf(v3) << 16);
      *(uint2*)(dst + g * 64 + tj * 4) = pk;
    }
  }
}

// ---- per-row L2 norm (over n=4096) of q and k ------------------------------
// grid (2048, 2): x = b*256+c, y: 0 = q rows, 1 = k rows
__global__ __launch_bounds__(256) void rownorm(
    const unsigned short* __restrict__ qkv,
    float* __restrict__ invq, float* __restrict__ invk)
{
  const int r = blockIdx.x;
  const int b = r >> 8, c = r & 255;
  const int ch = blockIdx.y * 256 + c;
  const ushort4* p = (const ushort4*)(qkv + ((size_t)b * 768 + ch) * NPIX);
  float s = 0.0f;
  for (int i = threadIdx.x; i < NPIX / 4; i += 256) {
    ushort4 u = p[i];
    float a = bf2f(u.x), bb = bf2f(u.y), cc2 = bf2f(u.z), d = bf2f(u.w);
    s += a * a + bb * bb + cc2 * cc2 + d * d;
  }
  __shared__ float red[256];
  red[threadIdx.x] = s;
  __syncthreads();
  for (int st = 128; st > 0; st >>= 1) {
    if (threadIdx.x < st) red[threadIdx.x] += red[threadIdx.x + st];
    __syncthreads();
  }
  if (threadIdx.x == 0) {
    float nrm = sqrtf(red[0]);
    float iv = 1.0f / fmaxf(nrm, 1e-12f);
    (blockIdx.y == 0 ? invq : invk)[r] = iv;
  }
}

// ---- partial qk^T over n-chunks of 256 -------------------------------------
// grid (16, 4, 8). out Spart[((b*4+h)*16+chunk)*4096 + c*64 + d]
__global__ __launch_bounds__(256) void spart_kernel(
    const unsigned short* __restrict__ qs, const unsigned short* __restrict__ ks,
    float* __restrict__ Sp)
{
  const int chunk = blockIdx.x, h = blockIdx.y, b = blockIdx.z;
  const int tid = threadIdx.x;
  const int ti = tid >> 4, tj = tid & 15;
  __shared__ float Qs[64][68];  // [n][c]
  __shared__ float Ks[64][68];  // [n][d]
  float acc[4][4] = {};
  const int cc = tid >> 4;
  const int n4 = (tid & 15) * 4;
  const size_t qbase = ((size_t)b * 768 + h * 64) * NPIX;
  const size_t kbase = ((size_t)b * 768 + 256 + h * 64) * NPIX;
  for (int sub = 0; sub < 4; ++sub) {
    const int noff = chunk * 256 + sub * 64;
    __syncthreads();
#pragma unroll
    for (int rr = 0; rr < 4; ++rr) {
      int row = cc + rr * 16;
      ushort4 uq = *(const ushort4*)&qs[qbase + (size_t)row * NPIX + noff + n4];
      ushort4 uk = *(const ushort4*)&ks[kbase + (size_t)row * NPIX + noff + n4];
      Qs[n4 + 0][row] = bf2f(uq.x); Qs[n4 + 1][row] = bf2f(uq.y);
      Qs[n4 + 2][row] = bf2f(uq.z); Qs[n4 + 3][row] = bf2f(uq.w);
      Ks[n4 + 0][row] = bf2f(uk.x); Ks[n4 + 1][row] = bf2f(uk.y);
      Ks[n4 + 2][row] = bf2f(uk.z); Ks[n4 + 3][row] = bf2f(uk.w);
    }
    __syncthreads();
#pragma unroll
    for (int kk = 0; kk < 64; ++kk) {
      float a[4], bb[4];
      *(float4*)a  = *(const float4*)&Qs[kk][ti * 4];
      *(float4*)bb = *(const float4*)&Ks[kk][tj * 4];
#pragma unroll
      for (int i = 0; i < 4; ++i)
#pragma unroll
        for (int j = 0; j < 4; ++j)
          acc[i][j] = fmaf(a[i], bb[j], acc[i][j]);
    }
  }
  float* dst = Sp + ((size_t)(b * 4 + h) * 16 + chunk) * 4096;
#pragma unroll
  for (int i = 0; i < 4; ++i)
    *(float4*)&dst[(ti * 4 + i) * 64 + tj * 4] = *(float4*)&acc[i][0];
}

// ---- reduce partials, scale by inv norms * temp, softmax over d ------------
// grid 32 = b*4+h; wave per 16 rows, lane = d
__global__ __launch_bounds__(256) void softattn(
    const float* __restrict__ Sp, const float* __restrict__ ivq,
    const float* __restrict__ ivk, float* __restrict__ attn)
{
  const int bh = blockIdx.x;
  const int b = bh >> 2, h = bh & 3;
  const int wv = threadIdx.x >> 6, lane = threadIdx.x & 63;
  const float ikd = ivk[b * 256 + h * 64 + lane];
  for (int c = wv; c < 64; c += 4) {
    float s = 0.0f;
#pragma unroll
    for (int ch = 0; ch < 16; ++ch)
      s += Sp[((size_t)bh * 16 + ch) * 4096 + c * 64 + lane];
    float z = s * 0.125f * ivq[b * 256 + h * 64 + c] * ikd;
    float m = z;
#pragma unroll
    for (int off = 32; off > 0; off >>= 1) m = fmaxf(m, __shfl_xor(m, off));
    float e = expf(z - m);
    float sum = e;
#pragma unroll
    for (int off = 32; off > 0; off >>= 1) sum += __shfl_xor(sum, off);
    attn[(size_t)bh * 4096 + c * 64 + lane] = e / sum;
  }
}

// ---- x_out = attn @ v (+ SE sum-pool partials) -----------------------------
// grid (64, 4, 8): 64n per block, K=d=64
__global__ __launch_bounds__(256) void av_kernel(
    const float* __restrict__ attn, const unsigned short* __restrict__ qkv,
    unsigned short* __restrict__ xout, float* __restrict__ pool)
{
  const int n0 = blockIdx.x * 64;
  const int h = blockIdx.y, b = blockIdx.z;
  const int tid = threadIdx.x;
  const int ti = tid >> 4, tj = tid & 15;
  __shared__ float As[64][68];   // [d][c]
  __shared__ float Vs[64][68];   // [d][n]
  __shared__ float red[64][17];
  const int bh = b * 4 + h;
  {
    const int cc = tid >> 4, q4 = (tid & 15) * 4;
#pragma unroll
    for (int rr = 0; rr < 4; ++rr) {
      int c = cc + rr * 16;
      float4 a4 = *(const float4*)&attn[(size_t)bh * 4096 + c * 64 + q4];
      As[q4 + 0][c] = a4.x; As[q4 + 1][c] = a4.y;
      As[q4 + 2][c] = a4.z; As[q4 + 3][c] = a4.w;
      int d = c;
      ushort4 u = *(const ushort4*)&qkv[((size_t)b * 768 + 512 + h * 64 + d) * NPIX + n0 + q4];
      Vs[d][q4 + 0] = bf2f(u.x); Vs[d][q4 + 1] = bf2f(u.y);
      Vs[d][q4 + 2] = bf2f(u.z); Vs[d][q4 + 3] = bf2f(u.w);
    }
  }
  __syncthreads();
  float acc[4][4] = {};
#pragma unroll
  for (int kk = 0; kk < 64; ++kk) {
    float a[4], vv[4];
    *(float4*)a  = *(const float4*)&As[kk][ti * 4];
    *(float4*)vv = *(const float4*)&Vs[kk][tj * 4];
#pragma unroll
    for (int i = 0; i < 4; ++i)
#pragma unroll
      for (int j = 0; j < 4; ++j)
        acc[i][j] = fmaf(a[i], vv[j], acc[i][j]);
  }
#pragma unroll
  for (int i = 0; i < 4; ++i) {
    int c = ti * 4 + i;
    int co = h * 64 + c;
    uint2 pk;
    pk.x = (unsigned)f2bf(acc[i][0]) | ((unsigned)f2bf(acc[i][1]) << 16);
    pk.y = (unsigned)f2bf(acc[i][2]) | ((unsigned)f2bf(acc[i][3]) << 16);
    *(uint2*)&xout[((size_t)b * 256 + co) * NPIX + n0 + tj * 4] = pk;
    red[c][tj] = acc[i][0] + acc[i][1] + acc[i][2] + acc[i][3];
  }
  __syncthreads();
  if (tid < 64) {
    float s = 0.0f;
#pragma unroll
    for (int t = 0; t < 16; ++t) s += red[tid][t];
    atomicAdd(&pool[b * 256 + h * 64 + tid], s);
  }
}

// ---- SE gate MLP ------------------------------------------------------------
__global__ __launch_bounds__(256) void segate(
    const float* __restrict__ pool, const float* __restrict__ w1,
    const float* __restrict__ b1, const float* __restrict__ w2,
    const float* __restrict__ b2, float* __restrict__ gate)
{
  const int b = blockIdx.x;
  const int tid = threadIdx.x;
  __shared__ float p[256];
  __shared__ float hh[32];
  p[tid] = pool[b * 256 + tid] * (1.0f / 4096.0f);
  __syncthreads();
  if (tid < 32) {
    float s = b1[tid];
    for (int c = 0; c < 256; ++c) s = fmaf(w1[tid * 256 + c], p[c], s);
    hh[tid] = fmaxf(s, 0.0f);
  }
  __syncthreads();
  float s = b2[tid];
#pragma unroll
  for (int r = 0; r < 32; ++r) s = fmaf(w2[tid * 32 + r], hh[r], s);
  gate[b * 256 + tid] = 1.0f / (1.0f + expf(-s));
}

// ---- final 1x1 projection + bias + residual --------------------------------
// grid (32, 2, 8)
__global__ __launch_bounds__(256) void pout_gemm(
    const unsigned short* __restrict__ xo, const float* __restrict__ gate,
    const float* __restrict__ W, const float* __restrict__ bias,
    const float* __restrict__ xres, float* __restrict__ out)
{
  const int n0 = blockIdx.x * 128;
  const int o0 = blockIdx.y * 128;
  const int b  = blockIdx.z;
  const int tid = threadIdx.x;
  const int ti = tid >> 4, tj = tid & 15;
  __shared__ float As[8][132];
  __shared__ float Bs[8][132];
  float acc[8][8] = {};
  const unsigned short* xob = xo + (size_t)b * 256 * NPIX;
  const int arow = tid >> 1, acol = (tid & 1) * 4;
  const int brow = tid >> 5, bcol = (tid & 31) * 4;
  for (int kc = 0; kc < 256; kc += 8) {
    float4 av4 = *(const float4*)&W[(size_t)(o0 + arow) * 256 + kc + acol];
    ushort4 u = *(const ushort4*)&xob[(size_t)(kc + brow) * NPIX + n0 + bcol];
    float g = gate[b * 256 + kc + brow];
    float4 bv4 = make_float4(bf2f(u.x) * g, bf2f(u.y) * g, bf2f(u.z) * g, bf2f(u.w) * g);
    __syncthreads();
    As[acol + 0][arow] = av4.x; As[acol + 1][arow] = av4.y;
    As[acol + 2][arow] = av4.z; As[acol + 3][arow] = av4.w;
    *(float4*)&Bs[brow][bcol] = bv4;
    __syncthreads();
#pragma unroll
    for (int kk = 0; kk < 8; ++kk) {
      float a[8], bb[8];
      *(float4*)&a[0] = *(const float4*)&As[kk][ti * 8];
      *(float4*)&a[4] = *(const float4*)&As[kk][ti * 8 + 4];
      *(float4*)&bb[0] = *(const float4*)&Bs[kk][tj * 4];
      *(float4*)&bb[4] = *(const float4*)&Bs[kk][64 + tj * 4];
#pragma unroll
      for (int i = 0; i < 8; ++i)
#pragma unroll
        for (int j = 0; j < 8; ++j)
          acc[i][j] = fmaf(a[i], bb[j], acc[i][j]);
    }
  }
#pragma unroll
  for (int i = 0; i < 8; ++i) {
    const int o = o0 + ti * 8 + i;
    const float bi = bias[o];
    const float* res = xres + ((size_t)b * 256 + o) * NPIX + n0;
    float* dst = out + ((size_t)b * 256 + o) * NPIX + n0;
#pragma unroll
    for (int g4 = 0; g4 < 2; ++g4) {
      float4 r = *(const float4*)(res + g4 * 64 + tj * 4);
      float4 ov;
      ov.x = acc[i][g4 * 4 + 0] + bi + r.x;
      ov.y = acc[i][g4 * 4 + 1] + bi + r.y;
      ov.z = acc[i][g4 * 4 + 2] + bi + r.z;
      ov.w = acc[i][g4 * 4 + 3] + bi + r.w;
      *(float4*)(dst + g4 * 64 + tj * 4) = ov;
    }
  }
}

extern "C" void kernel_launch(void* const* d_in, const int* in_sizes, int n_in,
                              void* d_out, int out_size, void* d_ws, size_t ws_size,
                              hipStream_t stream) {
  const float* x1    = (const float*)d_in[0];
  const float* x2    = (const float*)d_in[1];
  const float* ms_w3 = (const float*)d_in[2];
  const float* ms_b3 = (const float*)d_in[3];
  const float* ms_w5 = (const float*)d_in[4];
  const float* ms_b5 = (const float*)d_in[5];
  const float* ms_w7 = (const float*)d_in[6];
  const float* ms_b7 = (const float*)d_in[7];
  const float* qkv1_w = (const float*)d_in[8];
  const float* qkv1_b = (const float*)d_in[9];
  const float* bn1_g = (const float*)d_in[10];
  const float* bn1_b = (const float*)d_in[11];
  const float* bn1_m = (const float*)d_in[12];
  const float* bn1_v = (const float*)d_in[13];
  const float* qkv2_w = (const float*)d_in[14];
  const float* qkv2_b = (const float*)d_in[15];
  const float* bn2_g = (const float*)d_in[16];
  const float* bn2_b = (const float*)d_in[17];
  const float* bn2_m = (const float*)d_in[18];
  const float* bn2_v = (const float*)d_in[19];
  const float* ca_w1 = (const float*)d_in[20];
  const float* ca_b1 = (const float*)d_in[21];
  const float* ca_w2 = (const float*)d_in[22];
  const float* ca_b2 = (const float*)d_in[23];
  const float* po1_w = (const float*)d_in[24];
  const float* po1_b = (const float*)d_in[25];
  const float* po2_w = (const float*)d_in[26];
  const float* po2_b = (const float*)d_in[27];

  char* ws = (char*)d_ws;
  float* weff  = (float*)(ws + 0);
  float* beff  = (float*)(ws + 51200);
  float* alpha = (float*)(ws + 53248);
  float* beta  = (float*)(ws + 59392);
  float* invq  = (float*)(ws + 65536);
  float* invk  = (float*)(ws + 81920);
  float* pool  = (float*)(ws + 98304);
  float* gate  = (float*)(ws + 114688);
  float* attn1 = (float*)(ws + 1048576);
  float* attn2 = (float*)(ws + 1572864);
  float* Sp    = (float*)(ws + 2097152);
  float* xf    = (float*)(ws + 10485760);
  unsigned short* xout1 = (unsigned short*)(ws + 10485760);            // reuses xf
  unsigned short* xout2 = (unsigned short*)(ws + 10485760 + 16777216); // reuses xf
  unsigned short* qkv1  = (unsigned short*)(ws + 44040192);
  unsigned short* qkv2  = (unsigned short*)(ws + 94371840);

  float* outf = (float*)d_out;
  const size_t stream2_off = (size_t)8 * 256 * NPIX;

  prep_kernel<<<1, 256, 0, stream>>>(ms_w3, ms_b3, ms_w5, ms_b5, ms_w7, ms_b7,
                                     qkv1_b, bn1_g, bn1_b, bn1_m, bn1_v,
                                     qkv2_b, bn2_g, bn2_b, bn2_m, bn2_v,
                                     weff, beff, alpha, beta);

  // stream 1: multi-scale + qkv
  ms_conv<<<2048, 256, 0, stream>>>(x1, weff, beff, xf);
  qkv_gemm<<<dim3(32, 6, 8), 256, 0, stream>>>(xf, qkv1_w, alpha, beta, qkv1);
  // stream 2
  ms_conv<<<2048, 256, 0, stream>>>(x2, weff, beff, xf);
  qkv_gemm<<<dim3(32, 6, 8), 256, 0, stream>>>(xf, qkv2_w, alpha + 768, beta + 768, qkv2);

  // inverse L2 norms of q,k rows
  rownorm<<<dim3(2048, 2), 256, 0, stream>>>(qkv1, invq, invk);
  rownorm<<<dim3(2048, 2), 256, 0, stream>>>(qkv2, invq + 2048, invk + 2048);

  // attn1 = softmax(q1n . k2n * temp); attn2 = softmax(q2n . k1n * temp)
  spart_kernel<<<dim3(16, 4, 8), 256, 0, stream>>>(qkv1, qkv2, Sp);
  softattn<<<32, 256, 0, stream>>>(Sp, invq, invk + 2048, attn1);
  spart_kernel<<<dim3(16, 4, 8), 256, 0, stream>>>(qkv2, qkv1, Sp);
  softattn<<<32, 256, 0, stream>>>(Sp, invq + 2048, invk, attn2);

  // x_out = attn @ v  (+ pooled sums for SE)
  hipMemsetAsync(pool, 0, 2 * 2048 * sizeof(float), stream);
  av_kernel<<<dim3(64, 4, 8), 256, 0, stream>>>(attn1, qkv1, xout1, pool);
  av_kernel<<<dim3(64, 4, 8), 256, 0, stream>>>(attn2, qkv2, xout2, pool + 2048);

  // SE gates
  segate<<<8, 256, 0, stream>>>(pool, ca_w1, ca_b1, ca_w2, ca_b2, gate);
  segate<<<8, 256, 0, stream>>>(pool + 2048, ca_w1, ca_b1, ca_w2, ca_b2, gate + 2048);

  // final projection + residual
  pout_gemm<<<dim3(32, 2, 8), 256, 0, stream>>>(xout1, gate, po1_w, po1_b, x1, outf);
  pout_gemm<<<dim3(32, 2, 8), 256, 0, stream>>>(xout2, gate + 2048, po2_w, po2_b, x2,
                                                outf + stream2_off);
}

// Round 2
// 616.677 us; speedup vs baseline: 1.4526x; 1.4526x over previous
//
#include <hip/hip_runtime.h>
#include <hip/hip_bf16.h>

// ---------------------------------------------------------------------------
// SCFA fused pipeline, bf16 MFMA GEMMs (m97-style bt-GEMM), fp32 epilogues.
// B=8, C=256, N=4096, NH=4, HD=64.
// ---------------------------------------------------------------------------

#define NPIX 4096

typedef __attribute__((ext_vector_type(8))) short bfrag;   // 8 bf16 (4 VGPR)
typedef __attribute__((ext_vector_type(4))) float f4acc;   // 4 fp32 acc

#define GLDS16(g, l) __builtin_amdgcn_global_load_lds( \
    (const __attribute__((address_space(1))) unsigned int*)(g), \
    (__attribute__((address_space(3))) unsigned int*)(l), 16, 0, 0)

__device__ __forceinline__ float bf2f(unsigned short h) {
  return __uint_as_float(((unsigned)h) << 16);
}
__device__ __forceinline__ unsigned short f2bf(float f) {
  unsigned u = __float_as_uint(f);
  unsigned r = (u + 0x7FFFu + ((u >> 16) & 1u)) >> 16;
  return (unsigned short)r;
}
__device__ __forceinline__ float gelu_f(float x) {
  return 0.5f * x * (1.0f + erff(x * 0.70710678118654752440f));
}

// ---- prep: fold depthwise kernels, fold BN+bias ----------------------------
__global__ __launch_bounds__(256) void prep_kernel(
    const float* __restrict__ w3, const float* __restrict__ b3,
    const float* __restrict__ w5, const float* __restrict__ b5,
    const float* __restrict__ w7, const float* __restrict__ b7,
    const float* __restrict__ qb1, const float* __restrict__ g1,
    const float* __restrict__ be1, const float* __restrict__ m1,
    const float* __restrict__ v1,
    const float* __restrict__ qb2, const float* __restrict__ g2,
    const float* __restrict__ be2, const float* __restrict__ m2,
    const float* __restrict__ v2,
    float* __restrict__ weff, float* __restrict__ beff,
    float* __restrict__ alpha, float* __restrict__ beta)
{
  const int c = threadIdx.x;
  for (int ky = 0; ky < 7; ++ky)
    for (int kx = 0; kx < 7; ++kx) {
      float w = w7[c * 49 + ky * 7 + kx];
      if (ky >= 1 && ky <= 5 && kx >= 1 && kx <= 5)
        w += w5[c * 25 + (ky - 1) * 5 + (kx - 1)];
      if (ky >= 2 && ky <= 4 && kx >= 2 && kx <= 4)
        w += w3[c * 9 + (ky - 2) * 3 + (kx - 2)];
      weff[c * 49 + ky * 7 + kx] = w * (1.0f / 3.0f);
    }
  beff[c] = (b3[c] + b5[c] + b7[c]) * (1.0f / 3.0f);
  for (int o = c; o < 768; o += 256) {
    float inv1 = g1[o] / sqrtf(v1[o] + 1e-5f);
    alpha[o] = inv1;
    beta[o]  = qb1[o] * inv1 + be1[o] - m1[o] * inv1;
    float inv2 = g2[o] / sqrtf(v2[o] + 1e-5f);
    alpha[768 + o] = inv2;
    beta[768 + o]  = qb2[o] * inv2 + be2[o] - m2[o] * inv2;
  }
}

// ---- convert qkv weights fp32 -> bf16 (both streams) -----------------------
__global__ __launch_bounds__(256) void convert_w(
    const float* __restrict__ s1, const float* __restrict__ s2,
    unsigned short* __restrict__ d1, unsigned short* __restrict__ d2)
{
  int idx = blockIdx.x * 256 + threadIdx.x;   // grid 768 -> 196608 elems
  d1[idx] = f2bf(s1[idx]);
  d2[idx] = f2bf(s2[idx]);
}

// ---- fused multi-scale depthwise conv -> bf16 [c][n] -----------------------
__global__ __launch_bounds__(256) void ms_conv(
    const float* __restrict__ x, const float* __restrict__ weff,
    const float* __restrict__ beff, unsigned short* __restrict__ xf)
{
  __shared__ float tile[70 * 70];
  __shared__ float wsh[49];
  __shared__ float bsh;
  const int bc = blockIdx.x;      // b*256 + c
  const int c = bc & 255;
  const int tid = threadIdx.x;
  const float* src = x + (size_t)bc * NPIX;
  if (tid < 49) wsh[tid] = weff[c * 49 + tid];
  if (tid == 63) bsh = beff[c];
  for (int idx = tid; idx < 4900; idx += 256) {
    int yy = idx / 70, xx = idx - yy * 70;
    int gy = yy - 3, gx = xx - 3;
    float v = 0.0f;
    if ((unsigned)gy < 64u && (unsigned)gx < 64u) v = src[gy * 64 + gx];
    tile[idx] = v;
  }
  __syncthreads();
  const int tx = tid & 63;
  const int y0 = (tid >> 6) * 16;
  float win[7][7];
#pragma unroll
  for (int r = 0; r < 6; ++r)
#pragma unroll
    for (int k = 0; k < 7; ++k) win[r][k] = tile[(y0 + r) * 70 + tx + k];
  unsigned short* dst = xf + (size_t)bc * NPIX;
#pragma unroll
  for (int i = 0; i < 16; ++i) {
#pragma unroll
    for (int k = 0; k < 7; ++k)
      win[(i + 6) % 7][k] = tile[(y0 + i + 6) * 70 + tx + k];
    float s = bsh;
#pragma unroll
    for (int r = 0; r < 7; ++r)
#pragma unroll
      for (int k = 0; k < 7; ++k)
        s = fmaf(wsh[r * 7 + k], win[(i + r) % 7][k], s);
    dst[(y0 + i) * 64 + tx] = f2bf(s);
  }
}

// ---- bf16 [R=256 rows][4096] -> [4096][256] tile transpose -----------------
// grid (64 n-tiles, 4 c-tiles, 8 b)
__global__ __launch_bounds__(256) void transpose_bf16(
    const unsigned short* __restrict__ src, unsigned short* __restrict__ dst,
    long sb, long db)
{
  __shared__ unsigned short T[64][72];
  const int n0 = blockIdx.x * 64, c0 = blockIdx.y * 64, b = blockIdx.z;
  const int t = threadIdx.x;
  const int rhi = t >> 4, c4 = (t & 15) * 4;
#pragma unroll
  for (int rr = 0; rr < 4; ++rr) {
    int row = rr * 16 + rhi;
    ushort4 u = *(const ushort4*)&src[(size_t)b * sb + (size_t)(c0 + row) * NPIX + n0 + c4];
    T[row][c4 + 0] = u.x; T[row][c4 + 1] = u.y;
    T[row][c4 + 2] = u.z; T[row][c4 + 3] = u.w;
  }
  __syncthreads();
#pragma unroll
  for (int rr = 0; rr < 4; ++rr) {
    int nrow = rr * 16 + rhi;
    ushort4 u;
    u.x = T[c4 + 0][nrow]; u.y = T[c4 + 1][nrow];
    u.z = T[c4 + 2][nrow]; u.w = T[c4 + 3][nrow];
    *(ushort4*)&dst[(size_t)b * db + (size_t)(n0 + nrow) * 256 + c0 + c4] = u;
  }
}

// ---- qkv 1x1 GEMM (MFMA bt): D[o][n] = sum_k W[o][k]*Xt[n][k] --------------
// grid (32 n, 6 o, 8 b). BN+gelu epilogue, fused q/k row-sumsq atomics.
__global__ __launch_bounds__(256) void qkv_gemm(
    const unsigned short* __restrict__ Wb, const unsigned short* __restrict__ Xt,
    const float* __restrict__ alpha, const float* __restrict__ beta,
    unsigned short* __restrict__ qkv, float* __restrict__ normsq)
{
  __shared__ unsigned short As[128 * 64];
  __shared__ unsigned short Bs[128 * 64];
  const int n0 = blockIdx.x * 128, o0 = blockIdx.y * 128, b = blockIdx.z;
  const int tid = threadIdx.x, w = tid >> 6, lane = tid & 63;
  const int wm = (w & 1) * 64, wn = (w >> 1) * 64;
  const int lrow8 = lane >> 3, lcol8 = (lane & 7) * 8;   // for 64-el rows
  f4acc acc[4][4] = {};
  for (int kc = 0; kc < 256; kc += 64) {
    __syncthreads();
#pragma unroll
    for (int j = 0; j < 4; ++j) {
      int i = w * 4 + j;
      GLDS16(Wb + (size_t)(o0 + i * 8 + lrow8) * 256 + kc + lcol8, &As[i * 512]);
      GLDS16(Xt + (size_t)b * 1048576 + (size_t)(n0 + i * 8 + lrow8) * 256 + kc + lcol8,
             &Bs[i * 512]);
    }
    __syncthreads();
#pragma unroll
    for (int ks = 0; ks < 2; ++ks) {
      bfrag a[4], bb[4];
#pragma unroll
      for (int mt = 0; mt < 4; ++mt)
        a[mt] = *(const bfrag*)&As[(wm + mt * 16 + (lane & 15)) * 64 + ks * 32 + (lane >> 4) * 8];
#pragma unroll
      for (int nt = 0; nt < 4; ++nt)
        bb[nt] = *(const bfrag*)&Bs[(wn + nt * 16 + (lane & 15)) * 64 + ks * 32 + (lane >> 4) * 8];
#pragma unroll
      for (int mt = 0; mt < 4; ++mt)
#pragma unroll
        for (int nt = 0; nt < 4; ++nt)
          acc[mt][nt] = __builtin_amdgcn_mfma_f32_16x16x32_bf16(a[mt], bb[nt], acc[mt][nt], 0, 0, 0);
    }
  }
  // epilogue
#pragma unroll
  for (int mt = 0; mt < 4; ++mt) {
    const int or0 = o0 + wm + mt * 16 + (lane >> 4) * 4;
    float al[4], be[4], sq[4];
#pragma unroll
    for (int r = 0; r < 4; ++r) { al[r] = alpha[or0 + r]; be[r] = beta[or0 + r]; sq[r] = 0.0f; }
#pragma unroll
    for (int nt = 0; nt < 4; ++nt) {
      const int n = n0 + wn + nt * 16 + (lane & 15);
#pragma unroll
      for (int r = 0; r < 4; ++r) {
        float v = gelu_f(acc[mt][nt][r] * al[r] + be[r]);
        qkv[((size_t)b * 768 + or0 + r) * NPIX + n] = f2bf(v);
        sq[r] += v * v;
      }
    }
    if (or0 < 512) {  // q or k rows: accumulate row sum-of-squares
#pragma unroll
      for (int r = 0; r < 4; ++r) {
        float s = sq[r];
        s += __shfl_xor(s, 1); s += __shfl_xor(s, 2);
        s += __shfl_xor(s, 4); s += __shfl_xor(s, 8);
        if ((lane & 15) == 0) atomicAdd(&normsq[b * 512 + or0 + r], s);
      }
    }
  }
}

// ---- spart (MFMA): partial S[c][d] += sum_n q[c][n]*k[d][n] ----------------
// grid (8 chunks of 512 n, 4 h, 8 b)
__global__ __launch_bounds__(256) void spart_kernel(
    const unsigned short* __restrict__ qs, const unsigned short* __restrict__ ks,
    float* __restrict__ Sp)
{
  __shared__ unsigned short Qs[64 * 128];
  __shared__ unsigned short Ks[64 * 128];
  const int ck = blockIdx.x, h = blockIdx.y, b = blockIdx.z;
  const int tid = threadIdx.x, w = tid >> 6, lane = tid & 63;
  const int lrow16 = lane >> 4, lcol16 = (lane & 15) * 8;  // for 128-el rows
  const size_t qbase = ((size_t)b * 768 + h * 64) * NPIX;
  f4acc acc[4] = {};
  for (int it = 0; it < 4; ++it) {
    const int noff = ck * 512 + it * 128;
    __syncthreads();
#pragma unroll
    for (int j = 0; j < 4; ++j) {
      int i = w * 4 + j;
      int row = i * 4 + lrow16;
      GLDS16(qs + qbase + (size_t)row * NPIX + noff + lcol16, &Qs[i * 512]);
      GLDS16(ks + qbase + (size_t)row * NPIX + noff + lcol16, &Ks[i * 512]);
    }
    __syncthreads();
#pragma unroll
    for (int kk = 0; kk < 4; ++kk) {
      bfrag a = *(const bfrag*)&Qs[(w * 16 + (lane & 15)) * 128 + kk * 32 + (lane >> 4) * 8];
#pragma unroll
      for (int nt = 0; nt < 4; ++nt) {
        bfrag bb = *(const bfrag*)&Ks[(nt * 16 + (lane & 15)) * 128 + kk * 32 + (lane >> 4) * 8];
        acc[nt] = __builtin_amdgcn_mfma_f32_16x16x32_bf16(a, bb, acc[nt], 0, 0, 0);
      }
    }
  }
  float* dst = Sp + ((size_t)(ck * 32) + b * 4 + h) * 4096;
#pragma unroll
  for (int nt = 0; nt < 4; ++nt)
#pragma unroll
    for (int r = 0; r < 4; ++r)
      dst[(w * 16 + (lane >> 4) * 4 + r) * 64 + nt * 16 + (lane & 15)] = acc[nt][r];
}

// ---- reduce partials, scale by inv norms * temp, softmax, write bf16 -------
__global__ __launch_bounds__(256) void softattn(
    const float* __restrict__ Sp, const float* __restrict__ nsq,
    const float* __restrict__ nsk, unsigned short* __restrict__ attn)
{
  const int bh = blockIdx.x;
  const int b = bh >> 2, h = bh & 3;
  const int wv = threadIdx.x >> 6, lane = threadIdx.x & 63;
  const float ikd = 1.0f / fmaxf(sqrtf(nsk[b * 512 + 256 + h * 64 + lane]), 1e-12f);
  for (int c = wv; c < 64; c += 4) {
    float s = 0.0f;
#pragma unroll
    for (int ch = 0; ch < 8; ++ch)
      s += Sp[((size_t)(ch * 32) + bh) * 4096 + c * 64 + lane];
    const float iq = 1.0f / fmaxf(sqrtf(nsq[b * 512 + h * 64 + c]), 1e-12f);
    float z = s * 0.125f * iq * ikd;
    float m = z;
#pragma unroll
    for (int off = 32; off > 0; off >>= 1) m = fmaxf(m, __shfl_xor(m, off));
    float e = expf(z - m);
    float sum = e;
#pragma unroll
    for (int off = 32; off > 0; off >>= 1) sum += __shfl_xor(sum, off);
    attn[(size_t)bh * 4096 + c * 64 + lane] = f2bf(e / sum);
  }
}

// ---- av (MFMA): xout_t[n'][c] = sum_d v_t[n'][d]*attn[c][d] (+pool) --------
// grid (16 chunks of 256 n', 4 h, 8 b). xout_t batch stride db.
__global__ __launch_bounds__(256) void av_kernel(
    const unsigned short* __restrict__ vt, const unsigned short* __restrict__ attn,
    unsigned short* __restrict__ xout, long db, float* __restrict__ pool)
{
  __shared__ unsigned short Vs[256 * 64];
  __shared__ unsigned short At[64 * 64];
  const int n0 = blockIdx.x * 256, h = blockIdx.y, b = blockIdx.z;
  const int tid = threadIdx.x, w = tid >> 6, lane = tid & 63;
  const int lrow8 = lane >> 3, lcol8 = (lane & 7) * 8;
  const int bh = b * 4 + h;
#pragma unroll
  for (int j = 0; j < 8; ++j) {
    int i = w * 8 + j;
    GLDS16(vt + ((size_t)b * 1048576 + (size_t)(n0 + i * 8 + lrow8) * 256) + h * 64 + lcol8,
           &Vs[i * 512]);
  }
#pragma unroll
  for (int j = 0; j < 2; ++j) {
    int i = w * 2 + j;
    GLDS16(attn + (size_t)bh * 4096 + (size_t)(i * 8 + lrow8) * 64 + lcol8, &At[i * 512]);
  }
  __syncthreads();
  f4acc acc[4][4] = {};
#pragma unroll
  for (int ks = 0; ks < 2; ++ks) {
    bfrag a[4], bb[4];
#pragma unroll
    for (int mt = 0; mt < 4; ++mt)
      a[mt] = *(const bfrag*)&Vs[(w * 64 + mt * 16 + (lane & 15)) * 64 + ks * 32 + (lane >> 4) * 8];
#pragma unroll
    for (int nt = 0; nt < 4; ++nt)
      bb[nt] = *(const bfrag*)&At[(nt * 16 + (lane & 15)) * 64 + ks * 32 + (lane >> 4) * 8];
#pragma unroll
    for (int mt = 0; mt < 4; ++mt)
#pragma unroll
      for (int nt = 0; nt < 4; ++nt)
        acc[mt][nt] = __builtin_amdgcn_mfma_f32_16x16x32_bf16(a[mt], bb[nt], acc[mt][nt], 0, 0, 0);
  }
#pragma unroll
  for (int nt = 0; nt < 4; ++nt) {
    const int c = nt * 16 + (lane & 15);
    float cs = 0.0f;
#pragma unroll
    for (int mt = 0; mt < 4; ++mt) {
      const int nr = n0 + w * 64 + mt * 16 + (lane >> 4) * 4;
#pragma unroll
      for (int r = 0; r < 4; ++r) {
        float v = acc[mt][nt][r];
        xout[(size_t)b * db + (size_t)(nr + r) * 256 + h * 64 + c] = f2bf(v);
        cs += v;
      }
    }
    cs += __shfl_xor(cs, 16); cs += __shfl_xor(cs, 32);
    if ((lane >> 4) == 0) atomicAdd(&pool[b * 256 + h * 64 + c], cs);
  }
}

// ---- SE gate MLP ------------------------------------------------------------
__global__ __launch_bounds__(256) void segate(
    const float* __restrict__ pool, const float* __restrict__ w1,
    const float* __restrict__ b1, const float* __restrict__ w2,
    const float* __restrict__ b2, float* __restrict__ gate)
{
  const int b = blockIdx.x;
  const int tid = threadIdx.x;
  __shared__ float p[256];
  __shared__ float hh[32];
  p[tid] = pool[b * 256 + tid] * (1.0f / 4096.0f);
  __syncthreads();
  if (tid < 32) {
    float s = b1[tid];
    for (int c = 0; c < 256; ++c) s = fmaf(w1[tid * 256 + c], p[c], s);
    hh[tid] = fmaxf(s, 0.0f);
  }
  __syncthreads();
  float s = b2[tid];
#pragma unroll
  for (int r = 0; r < 32; ++r) s = fmaf(w2[tid * 32 + r], hh[r], s);
  gate[b * 256 + tid] = 1.0f / (1.0f + expf(-s));
}

// ---- fold SE gate into per-batch bf16 output-proj weights ------------------
__global__ __launch_bounds__(256) void scale_w(
    const float* __restrict__ W, const float* __restrict__ gate,
    unsigned short* __restrict__ Wg)
{
  const int b = blockIdx.x, tid = threadIdx.x;
  const float g = gate[b * 256 + tid];
  for (int o = 0; o < 256; ++o)
    Wg[(size_t)b * 65536 + o * 256 + tid] = f2bf(W[o * 256 + tid] * g);
}

// ---- pout (MFMA): out[o][n] = sum_c Wg[o][c]*xout_t[n][c] + bias + res -----
// grid (32 n, 2 o, 8 b). xout_t batch stride db.
__global__ __launch_bounds__(256) void pout_gemm(
    const unsigned short* __restrict__ Wg, const unsigned short* __restrict__ Xt,
    long db, const float* __restrict__ bias, const float* __restrict__ xres,
    float* __restrict__ out)
{
  __shared__ unsigned short As[128 * 64];
  __shared__ unsigned short Bs[128 * 64];
  const int n0 = blockIdx.x * 128, o0 = blockIdx.y * 128, b = blockIdx.z;
  const int tid = threadIdx.x, w = tid >> 6, lane = tid & 63;
  const int wm = (w & 1) * 64, wn = (w >> 1) * 64;
  const int lrow8 = lane >> 3, lcol8 = (lane & 7) * 8;
  f4acc acc[4][4] = {};
  for (int kc = 0; kc < 256; kc += 64) {
    __syncthreads();
#pragma unroll
    for (int j = 0; j < 4; ++j) {
      int i = w * 4 + j;
      GLDS16(Wg + (size_t)b * 65536 + (size_t)(o0 + i * 8 + lrow8) * 256 + kc + lcol8,
             &As[i * 512]);
      GLDS16(Xt + (size_t)b * db + (size_t)(n0 + i * 8 + lrow8) * 256 + kc + lcol8,
             &Bs[i * 512]);
    }
    __syncthreads();
#pragma unroll
    for (int ks = 0; ks < 2; ++ks) {
      bfrag a[4], bb[4];
#pragma unroll
      for (int mt = 0; mt < 4; ++mt)
        a[mt] = *(const bfrag*)&As[(wm + mt * 16 + (lane & 15)) * 64 + ks * 32 + (lane >> 4) * 8];
#pragma unroll
      for (int nt = 0; nt < 4; ++nt)
        bb[nt] = *(const bfrag*)&Bs[(wn + nt * 16 + (lane & 15)) * 64 + ks * 32 + (lane >> 4) * 8];
#pragma unroll
      for (int mt = 0; mt < 4; ++mt)
#pragma unroll
        for (int nt = 0; nt < 4; ++nt)
          acc[mt][nt] = __builtin_amdgcn_mfma_f32_16x16x32_bf16(a[mt], bb[nt], acc[mt][nt], 0, 0, 0);
    }
  }
#pragma unroll
  for (int mt = 0; mt < 4; ++mt) {
    const int or0 = o0 + wm + mt * 16 + (lane >> 4) * 4;
    float bi[4];
#pragma unroll
    for (int r = 0; r < 4; ++r) bi[r] = bias[or0 + r];
#pragma unroll
    for (int nt = 0; nt < 4; ++nt) {
      const int n = n0 + wn + nt * 16 + (lane & 15);
#pragma unroll
      for (int r = 0; r < 4; ++r) {
        const size_t idx = ((size_t)b * 256 + or0 + r) * NPIX + n;
        out[idx] = acc[mt][nt][r] + bi[r] + xres[idx];
      }
    }
  }
}

extern "C" void kernel_launch(void* const* d_in, const int* in_sizes, int n_in,
                              void* d_out, int out_size, void* d_ws, size_t ws_size,
                              hipStream_t stream) {
  const float* x1    = (const float*)d_in[0];
  const float* x2    = (const float*)d_in[1];
  const float* ms_w3 = (const float*)d_in[2];
  const float* ms_b3 = (const float*)d_in[3];
  const float* ms_w5 = (const float*)d_in[4];
  const float* ms_b5 = (const float*)d_in[5];
  const float* ms_w7 = (const float*)d_in[6];
  const float* ms_b7 = (const float*)d_in[7];
  const float* qkv1_w = (const float*)d_in[8];
  const float* qkv1_b = (const float*)d_in[9];
  const float* bn1_g = (const float*)d_in[10];
  const float* bn1_b = (const float*)d_in[11];
  const float* bn1_m = (const float*)d_in[12];
  const float* bn1_v = (const float*)d_in[13];
  const float* qkv2_w = (const float*)d_in[14];
  const float* qkv2_b = (const float*)d_in[15];
  const float* bn2_g = (const float*)d_in[16];
  const float* bn2_b = (const float*)d_in[17];
  const float* bn2_m = (const float*)d_in[18];
  const float* bn2_v = (const float*)d_in[19];
  const float* ca_w1 = (const float*)d_in[20];
  const float* ca_b1 = (const float*)d_in[21];
  const float* ca_w2 = (const float*)d_in[22];
  const float* ca_b2 = (const float*)d_in[23];
  const float* po1_w = (const float*)d_in[24];
  const float* po1_b = (const float*)d_in[25];
  const float* po2_w = (const float*)d_in[26];
  const float* po2_b = (const float*)d_in[27];

  char* ws = (char*)d_ws;
  float* weff  = (float*)(ws + 0);
  float* beff  = (float*)(ws + 51200);
  float* alpha = (float*)(ws + 53248);
  float* beta  = (float*)(ws + 59392);
  float* normsq1 = (float*)(ws + 65536);   // 8*512 fp32
  float* normsq2 = (float*)(ws + 81920);
  float* pool  = (float*)(ws + 98304);     // 2*2048 fp32
  float* gate  = (float*)(ws + 114688);
  unsigned short* W1b = (unsigned short*)(ws + 131072);
  unsigned short* W2b = (unsigned short*)(ws + 524288);
  unsigned short* Wg1 = (unsigned short*)(ws + 917504);
  unsigned short* Wg2 = (unsigned short*)(ws + 1966080);
  unsigned short* attn1 = (unsigned short*)(ws + 3014656);
  unsigned short* attn2 = (unsigned short*)(ws + 3276800);
  float* Sp    = (float*)(ws + 3538944);   // 8*32*4096 fp32
  unsigned short* xf   = (unsigned short*)(ws + 7733248);   // [b][256][4096]
  unsigned short* xf_t = (unsigned short*)(ws + 24510464);  // [b][4096][256]
  unsigned short* qkv1 = (unsigned short*)(ws + 41287680);  // [b][768][4096]
  unsigned short* qkv2 = (unsigned short*)(ws + 91619328);
  // aliased (dead-region reuse):
  unsigned short* v1t   = xf;     // after xf consumed by transpose2
  unsigned short* v2t   = xf_t;   // after xf_t consumed by qkv_gemm2
  unsigned short* xout1 = qkv2;   // per-batch [n][256] in dead q/k chunks, stride 768*4096
  unsigned short* xout2 = qkv1;
  const long QKV_BSTR = 768L * 4096;

  float* outf = (float*)d_out;
  const size_t stream2_off = (size_t)8 * 256 * NPIX;

  prep_kernel<<<1, 256, 0, stream>>>(ms_w3, ms_b3, ms_w5, ms_b5, ms_w7, ms_b7,
                                     qkv1_b, bn1_g, bn1_b, bn1_m, bn1_v,
                                     qkv2_b, bn2_g, bn2_b, bn2_m, bn2_v,
                                     weff, beff, alpha, beta);
  convert_w<<<768, 256, 0, stream>>>(qkv1_w, qkv2_w, W1b, W2b);
  hipMemsetAsync(ws + 65536, 0, 49152, stream);  // normsq1/2 + pool

  // stream 1: conv -> transpose -> qkv GEMM
  ms_conv<<<2048, 256, 0, stream>>>(x1, weff, beff, xf);
  transpose_bf16<<<dim3(64, 4, 8), 256, 0, stream>>>(xf, xf_t, 1048576L, 1048576L);
  qkv_gemm<<<dim3(32, 6, 8), 256, 0, stream>>>(W1b, xf_t, alpha, beta, qkv1, normsq1);
  // stream 2
  ms_conv<<<2048, 256, 0, stream>>>(x2, weff, beff, xf);
  transpose_bf16<<<dim3(64, 4, 8), 256, 0, stream>>>(xf, xf_t, 1048576L, 1048576L);
  qkv_gemm<<<dim3(32, 6, 8), 256, 0, stream>>>(W2b, xf_t, alpha + 768, beta + 768, qkv2, normsq2);

  // attention logits + softmax (attn1: q1.k2, attn2: q2.k1)
  spart_kernel<<<dim3(8, 4, 8), 256, 0, stream>>>(qkv1, qkv2 + 256 * NPIX, Sp);
  softattn<<<32, 256, 0, stream>>>(Sp, normsq1, normsq2, attn1);
  spart_kernel<<<dim3(8, 4, 8), 256, 0, stream>>>(qkv2, qkv1 + 256 * NPIX, Sp);
  softattn<<<32, 256, 0, stream>>>(Sp, normsq2, normsq1, attn2);

  // v transposes (into dead xf / xf_t)
  transpose_bf16<<<dim3(64, 4, 8), 256, 0, stream>>>(qkv1 + 512 * NPIX, v1t, 3145728L, 1048576L);
  transpose_bf16<<<dim3(64, 4, 8), 256, 0, stream>>>(qkv2 + 512 * NPIX, v2t, 3145728L, 1048576L);

  // xout_t = v_t . attn^T  (+ SE pooling)
  av_kernel<<<dim3(16, 4, 8), 256, 0, stream>>>(v1t, attn1, xout1, QKV_BSTR, pool);
  av_kernel<<<dim3(16, 4, 8), 256, 0, stream>>>(v2t, attn2, xout2, QKV_BSTR, pool + 2048);

  // SE gates, fold into output-proj weights
  segate<<<8, 256, 0, stream>>>(pool, ca_w1, ca_b1, ca_w2, ca_b2, gate);
  segate<<<8, 256, 0, stream>>>(pool + 2048, ca_w1, ca_b1, ca_w2, ca_b2, gate + 2048);
  scale_w<<<8, 256, 0, stream>>>(po1_w, gate, Wg1);
  scale_w<<<8, 256, 0, stream>>>(po2_w, gate + 2048, Wg2);

  // final projection + bias + residual
  pout_gemm<<<dim3(32, 2, 8), 256, 0, stream>>>(Wg1, xout1, QKV_BSTR, po1_b, x1, outf);
  pout_gemm<<<dim3(32, 2, 8), 256, 0, stream>>>(Wg2, xout2, QKV_BSTR, po2_b, x2,
                                                outf + stream2_off);
}

// Round 3
// 556.228 us; speedup vs baseline: 1.6105x; 1.1087x over previous
//
#include <hip/hip_runtime.h>
#include <hip/hip_bf16.h>

// ---------------------------------------------------------------------------
// SCFA fused pipeline, bf16 MFMA GEMMs (m97-style bt-GEMM), fp32 epilogues.
// B=8, C=256, N=4096, NH=4, HD=64.
// R3: ms_conv rewritten — 4x4 px/thread, ds_read_b128 row segments, weights
// in SGPRs (block-uniform). LDS reads/px: 49 -> 1.9.
// ---------------------------------------------------------------------------

#define NPIX 4096

typedef __attribute__((ext_vector_type(8))) short bfrag;   // 8 bf16 (4 VGPR)
typedef __attribute__((ext_vector_type(4))) float f4acc;   // 4 fp32 acc

#define GLDS16(g, l) __builtin_amdgcn_global_load_lds( \
    (const __attribute__((address_space(1))) unsigned int*)(g), \
    (__attribute__((address_space(3))) unsigned int*)(l), 16, 0, 0)

__device__ __forceinline__ float bf2f(unsigned short h) {
  return __uint_as_float(((unsigned)h) << 16);
}
__device__ __forceinline__ unsigned short f2bf(float f) {
  unsigned u = __float_as_uint(f);
  unsigned r = (u + 0x7FFFu + ((u >> 16) & 1u)) >> 16;
  return (unsigned short)r;
}
__device__ __forceinline__ float gelu_f(float x) {
  return 0.5f * x * (1.0f + erff(x * 0.70710678118654752440f));
}

// ---- prep: fold depthwise kernels, fold BN+bias ----------------------------
__global__ __launch_bounds__(256) void prep_kernel(
    const float* __restrict__ w3, const float* __restrict__ b3,
    const float* __restrict__ w5, const float* __restrict__ b5,
    const float* __restrict__ w7, const float* __restrict__ b7,
    const float* __restrict__ qb1, const float* __restrict__ g1,
    const float* __restrict__ be1, const float* __restrict__ m1,
    const float* __restrict__ v1,
    const float* __restrict__ qb2, const float* __restrict__ g2,
    const float* __restrict__ be2, const float* __restrict__ m2,
    const float* __restrict__ v2,
    float* __restrict__ weff, float* __restrict__ beff,
    float* __restrict__ alpha, float* __restrict__ beta)
{
  const int c = threadIdx.x;
  for (int ky = 0; ky < 7; ++ky)
    for (int kx = 0; kx < 7; ++kx) {
      float w = w7[c * 49 + ky * 7 + kx];
      if (ky >= 1 && ky <= 5 && kx >= 1 && kx <= 5)
        w += w5[c * 25 + (ky - 1) * 5 + (kx - 1)];
      if (ky >= 2 && ky <= 4 && kx >= 2 && kx <= 4)
        w += w3[c * 9 + (ky - 2) * 3 + (kx - 2)];
      weff[c * 49 + ky * 7 + kx] = w * (1.0f / 3.0f);
    }
  beff[c] = (b3[c] + b5[c] + b7[c]) * (1.0f / 3.0f);
  for (int o = c; o < 768; o += 256) {
    float inv1 = g1[o] / sqrtf(v1[o] + 1e-5f);
    alpha[o] = inv1;
    beta[o]  = qb1[o] * inv1 + be1[o] - m1[o] * inv1;
    float inv2 = g2[o] / sqrtf(v2[o] + 1e-5f);
    alpha[768 + o] = inv2;
    beta[768 + o]  = qb2[o] * inv2 + be2[o] - m2[o] * inv2;
  }
}

// ---- convert qkv weights fp32 -> bf16 (both streams) -----------------------
__global__ __launch_bounds__(256) void convert_w(
    const float* __restrict__ s1, const float* __restrict__ s2,
    unsigned short* __restrict__ d1, unsigned short* __restrict__ d2)
{
  int idx = blockIdx.x * 256 + threadIdx.x;   // grid 768 -> 196608 elems
  d1[idx] = f2bf(s1[idx]);
  d2[idx] = f2bf(s2[idx]);
}

// ---- fused multi-scale depthwise conv -> bf16 [c][n] -----------------------
// Block = one (b,c) channel image (64x64). Thread = 4x4 output tile.
// LDS tile 70 rows x 76 cols fp32: input (y,x) at tile[y+3][x+4].
// Per input row: 3 ds_read_b128 (12-float seg), FMAs vs SGPR weights.
__global__ __launch_bounds__(256) void ms_conv(
    const float* __restrict__ x, const float* __restrict__ weff,
    const float* __restrict__ beff, unsigned short* __restrict__ xf)
{
  __shared__ float tile[70][76];
  const int bc = blockIdx.x;      // b*256 + c
  const int c = bc & 255;
  const int tid = threadIdx.x;
  const float* src = x + (size_t)bc * NPIX;
  // block-uniform weights -> scalar loads (SGPRs)
  float wreg[49];
#pragma unroll
  for (int i = 0; i < 49; ++i) wreg[i] = weff[c * 49 + i];
  const float bias = beff[c];
  // fill LDS tile (zero-padded halo)
  for (int idx = tid; idx < 70 * 76; idx += 256) {
    int ry = idx / 76, cx = idx - ry * 76;
    int gy = ry - 3, gx = cx - 4;
    float v = 0.0f;
    if ((unsigned)gy < 64u && (unsigned)gx < 64u) v = src[gy * 64 + gx];
    tile[ry][cx] = v;
  }
  __syncthreads();
  const int x0 = (tid & 15) * 4;
  const int y0 = (tid >> 4) * 4;
  float acc[4][4];
#pragma unroll
  for (int yo = 0; yo < 4; ++yo)
#pragma unroll
    for (int xo = 0; xo < 4; ++xo) acc[yo][xo] = bias;
#pragma unroll
  for (int r = 0; r < 10; ++r) {
    // input row iy = y0 + r - 3 -> tile row y0 + r; seg[j] = input col x0+j-4
    float seg[12];
    *(float4*)&seg[0] = *(const float4*)&tile[y0 + r][x0];
    *(float4*)&seg[4] = *(const float4*)&tile[y0 + r][x0 + 4];
    *(float4*)&seg[8] = *(const float4*)&tile[y0 + r][x0 + 8];
    const int yolo = (r >= 6) ? (r - 6) : 0;
    const int yohi = (r < 3) ? r : 3;
#pragma unroll
    for (int yo = 0; yo < 4; ++yo) {
      if (yo < yolo || yo > yohi) continue;
      const int ky = r - yo;
#pragma unroll
      for (int kx = 0; kx < 7; ++kx) {
        const float w = wreg[ky * 7 + kx];
#pragma unroll
        for (int xo = 0; xo < 4; ++xo)
          acc[yo][xo] = fmaf(w, seg[1 + xo + kx], acc[yo][xo]);
      }
    }
  }
  unsigned short* dst = xf + (size_t)bc * NPIX;
#pragma unroll
  for (int yo = 0; yo < 4; ++yo) {
    ushort4 u;
    u.x = f2bf(acc[yo][0]); u.y = f2bf(acc[yo][1]);
    u.z = f2bf(acc[yo][2]); u.w = f2bf(acc[yo][3]);
    *(ushort4*)&dst[(y0 + yo) * 64 + x0] = u;
  }
}

// ---- bf16 [R=256 rows][4096] -> [4096][256] tile transpose -----------------
// grid (64 n-tiles, 4 c-tiles, 8 b)
__global__ __launch_bounds__(256) void transpose_bf16(
    const unsigned short* __restrict__ src, unsigned short* __restrict__ dst,
    long sb, long db)
{
  __shared__ unsigned short T[64][72];
  const int n0 = blockIdx.x * 64, c0 = blockIdx.y * 64, b = blockIdx.z;
  const int t = threadIdx.x;
  const int rhi = t >> 4, c4 = (t & 15) * 4;
#pragma unroll
  for (int rr = 0; rr < 4; ++rr) {
    int row = rr * 16 + rhi;
    ushort4 u = *(const ushort4*)&src[(size_t)b * sb + (size_t)(c0 + row) * NPIX + n0 + c4];
    T[row][c4 + 0] = u.x; T[row][c4 + 1] = u.y;
    T[row][c4 + 2] = u.z; T[row][c4 + 3] = u.w;
  }
  __syncthreads();
#pragma unroll
  for (int rr = 0; rr < 4; ++rr) {
    int nrow = rr * 16 + rhi;
    ushort4 u;
    u.x = T[c4 + 0][nrow]; u.y = T[c4 + 1][nrow];
    u.z = T[c4 + 2][nrow]; u.w = T[c4 + 3][nrow];
    *(ushort4*)&dst[(size_t)b * db + (size_t)(n0 + nrow) * 256 + c0 + c4] = u;
  }
}

// ---- qkv 1x1 GEMM (MFMA bt): D[o][n] = sum_k W[o][k]*Xt[n][k] --------------
// grid (32 n, 6 o, 8 b). BN+gelu epilogue, fused q/k row-sumsq atomics.
__global__ __launch_bounds__(256) void qkv_gemm(
    const unsigned short* __restrict__ Wb, const unsigned short* __restrict__ Xt,
    const float* __restrict__ alpha, const float* __restrict__ beta,
    unsigned short* __restrict__ qkv, float* __restrict__ normsq)
{
  __shared__ unsigned short As[128 * 64];
  __shared__ unsigned short Bs[128 * 64];
  const int n0 = blockIdx.x * 128, o0 = blockIdx.y * 128, b = blockIdx.z;
  const int tid = threadIdx.x, w = tid >> 6, lane = tid & 63;
  const int wm = (w & 1) * 64, wn = (w >> 1) * 64;
  const int lrow8 = lane >> 3, lcol8 = (lane & 7) * 8;   // for 64-el rows
  f4acc acc[4][4] = {};
  for (int kc = 0; kc < 256; kc += 64) {
    __syncthreads();
#pragma unroll
    for (int j = 0; j < 4; ++j) {
      int i = w * 4 + j;
      GLDS16(Wb + (size_t)(o0 + i * 8 + lrow8) * 256 + kc + lcol8, &As[i * 512]);
      GLDS16(Xt + (size_t)b * 1048576 + (size_t)(n0 + i * 8 + lrow8) * 256 + kc + lcol8,
             &Bs[i * 512]);
    }
    __syncthreads();
#pragma unroll
    for (int ks = 0; ks < 2; ++ks) {
      bfrag a[4], bb[4];
#pragma unroll
      for (int mt = 0; mt < 4; ++mt)
        a[mt] = *(const bfrag*)&As[(wm + mt * 16 + (lane & 15)) * 64 + ks * 32 + (lane >> 4) * 8];
#pragma unroll
      for (int nt = 0; nt < 4; ++nt)
        bb[nt] = *(const bfrag*)&Bs[(wn + nt * 16 + (lane & 15)) * 64 + ks * 32 + (lane >> 4) * 8];
#pragma unroll
      for (int mt = 0; mt < 4; ++mt)
#pragma unroll
        for (int nt = 0; nt < 4; ++nt)
          acc[mt][nt] = __builtin_amdgcn_mfma_f32_16x16x32_bf16(a[mt], bb[nt], acc[mt][nt], 0, 0, 0);
    }
  }
  // epilogue
#pragma unroll
  for (int mt = 0; mt < 4; ++mt) {
    const int or0 = o0 + wm + mt * 16 + (lane >> 4) * 4;
    float al[4], be[4], sq[4];
#pragma unroll
    for (int r = 0; r < 4; ++r) { al[r] = alpha[or0 + r]; be[r] = beta[or0 + r]; sq[r] = 0.0f; }
#pragma unroll
    for (int nt = 0; nt < 4; ++nt) {
      const int n = n0 + wn + nt * 16 + (lane & 15);
#pragma unroll
      for (int r = 0; r < 4; ++r) {
        float v = gelu_f(acc[mt][nt][r] * al[r] + be[r]);
        qkv[((size_t)b * 768 + or0 + r) * NPIX + n] = f2bf(v);
        sq[r] += v * v;
      }
    }
    if (or0 < 512) {  // q or k rows: accumulate row sum-of-squares
#pragma unroll
      for (int r = 0; r < 4; ++r) {
        float s = sq[r];
        s += __shfl_xor(s, 1); s += __shfl_xor(s, 2);
        s += __shfl_xor(s, 4); s += __shfl_xor(s, 8);
        if ((lane & 15) == 0) atomicAdd(&normsq[b * 512 + or0 + r], s);
      }
    }
  }
}

// ---- spart (MFMA): partial S[c][d] += sum_n q[c][n]*k[d][n] ----------------
// grid (8 chunks of 512 n, 4 h, 8 b)
__global__ __launch_bounds__(256) void spart_kernel(
    const unsigned short* __restrict__ qs, const unsigned short* __restrict__ ks,
    float* __restrict__ Sp)
{
  __shared__ unsigned short Qs[64 * 128];
  __shared__ unsigned short Ks[64 * 128];
  const int ck = blockIdx.x, h = blockIdx.y, b = blockIdx.z;
  const int tid = threadIdx.x, w = tid >> 6, lane = tid & 63;
  const int lrow16 = lane >> 4, lcol16 = (lane & 15) * 8;  // for 128-el rows
  const size_t qbase = ((size_t)b * 768 + h * 64) * NPIX;
  f4acc acc[4] = {};
  for (int it = 0; it < 4; ++it) {
    const int noff = ck * 512 + it * 128;
    __syncthreads();
#pragma unroll
    for (int j = 0; j < 4; ++j) {
      int i = w * 4 + j;
      int row = i * 4 + lrow16;
      GLDS16(qs + qbase + (size_t)row * NPIX + noff + lcol16, &Qs[i * 512]);
      GLDS16(ks + qbase + (size_t)row * NPIX + noff + lcol16, &Ks[i * 512]);
    }
    __syncthreads();
#pragma unroll
    for (int kk = 0; kk < 4; ++kk) {
      bfrag a = *(const bfrag*)&Qs[(w * 16 + (lane & 15)) * 128 + kk * 32 + (lane >> 4) * 8];
#pragma unroll
      for (int nt = 0; nt < 4; ++nt) {
        bfrag bb = *(const bfrag*)&Ks[(nt * 16 + (lane & 15)) * 128 + kk * 32 + (lane >> 4) * 8];
        acc[nt] = __builtin_amdgcn_mfma_f32_16x16x32_bf16(a, bb, acc[nt], 0, 0, 0);
      }
    }
  }
  float* dst = Sp + ((size_t)(ck * 32) + b * 4 + h) * 4096;
#pragma unroll
  for (int nt = 0; nt < 4; ++nt)
#pragma unroll
    for (int r = 0; r < 4; ++r)
      dst[(w * 16 + (lane >> 4) * 4 + r) * 64 + nt * 16 + (lane & 15)] = acc[nt][r];
}

// ---- reduce partials, scale by inv norms * temp, softmax, write bf16 -------
__global__ __launch_bounds__(256) void softattn(
    const float* __restrict__ Sp, const float* __restrict__ nsq,
    const float* __restrict__ nsk, unsigned short* __restrict__ attn)
{
  const int bh = blockIdx.x;
  const int b = bh >> 2, h = bh & 3;
  const int wv = threadIdx.x >> 6, lane = threadIdx.x & 63;
  const float ikd = 1.0f / fmaxf(sqrtf(nsk[b * 512 + 256 + h * 64 + lane]), 1e-12f);
  for (int c = wv; c < 64; c += 4) {
    float s = 0.0f;
#pragma unroll
    for (int ch = 0; ch < 8; ++ch)
      s += Sp[((size_t)(ch * 32) + bh) * 4096 + c * 64 + lane];
    const float iq = 1.0f / fmaxf(sqrtf(nsq[b * 512 + h * 64 + c]), 1e-12f);
    float z = s * 0.125f * iq * ikd;
    float m = z;
#pragma unroll
    for (int off = 32; off > 0; off >>= 1) m = fmaxf(m, __shfl_xor(m, off));
    float e = expf(z - m);
    float sum = e;
#pragma unroll
    for (int off = 32; off > 0; off >>= 1) sum += __shfl_xor(sum, off);
    attn[(size_t)bh * 4096 + c * 64 + lane] = f2bf(e / sum);
  }
}

// ---- av (MFMA): xout_t[n'][c] = sum_d v_t[n'][d]*attn[c][d] (+pool) --------
// grid (16 chunks of 256 n', 4 h, 8 b). xout_t batch stride db.
__global__ __launch_bounds__(256) void av_kernel(
    const unsigned short* __restrict__ vt, const unsigned short* __restrict__ attn,
    unsigned short* __restrict__ xout, long db, float* __restrict__ pool)
{
  __shared__ unsigned short Vs[256 * 64];
  __shared__ unsigned short At[64 * 64];
  const int n0 = blockIdx.x * 256, h = blockIdx.y, b = blockIdx.z;
  const int tid = threadIdx.x, w = tid >> 6, lane = tid & 63;
  const int lrow8 = lane >> 3, lcol8 = (lane & 7) * 8;
  const int bh = b * 4 + h;
#pragma unroll
  for (int j = 0; j < 8; ++j) {
    int i = w * 8 + j;
    GLDS16(vt + ((size_t)b * 1048576 + (size_t)(n0 + i * 8 + lrow8) * 256) + h * 64 + lcol8,
           &Vs[i * 512]);
  }
#pragma unroll
  for (int j = 0; j < 2; ++j) {
    int i = w * 2 + j;
    GLDS16(attn + (size_t)bh * 4096 + (size_t)(i * 8 + lrow8) * 64 + lcol8, &At[i * 512]);
  }
  __syncthreads();
  f4acc acc[4][4] = {};
#pragma unroll
  for (int ks = 0; ks < 2; ++ks) {
    bfrag a[4], bb[4];
#pragma unroll
    for (int mt = 0; mt < 4; ++mt)
      a[mt] = *(const bfrag*)&Vs[(w * 64 + mt * 16 + (lane & 15)) * 64 + ks * 32 + (lane >> 4) * 8];
#pragma unroll
    for (int nt = 0; nt < 4; ++nt)
      bb[nt] = *(const bfrag*)&At[(nt * 16 + (lane & 15)) * 64 + ks * 32 + (lane >> 4) * 8];
#pragma unroll
    for (int mt = 0; mt < 4; ++mt)
#pragma unroll
      for (int nt = 0; nt < 4; ++nt)
        acc[mt][nt] = __builtin_amdgcn_mfma_f32_16x16x32_bf16(a[mt], bb[nt], acc[mt][nt], 0, 0, 0);
  }
#pragma unroll
  for (int nt = 0; nt < 4; ++nt) {
    const int c = nt * 16 + (lane & 15);
    float cs = 0.0f;
#pragma unroll
    for (int mt = 0; mt < 4; ++mt) {
      const int nr = n0 + w * 64 + mt * 16 + (lane >> 4) * 4;
#pragma unroll
      for (int r = 0; r < 4; ++r) {
        float v = acc[mt][nt][r];
        xout[(size_t)b * db + (size_t)(nr + r) * 256 + h * 64 + c] = f2bf(v);
        cs += v;
      }
    }
    cs += __shfl_xor(cs, 16); cs += __shfl_xor(cs, 32);
    if ((lane >> 4) == 0) atomicAdd(&pool[b * 256 + h * 64 + c], cs);
  }
}

// ---- SE gate MLP ------------------------------------------------------------
__global__ __launch_bounds__(256) void segate(
    const float* __restrict__ pool, const float* __restrict__ w1,
    const float* __restrict__ b1, const float* __restrict__ w2,
    const float* __restrict__ b2, float* __restrict__ gate)
{
  const int b = blockIdx.x;
  const int tid = threadIdx.x;
  __shared__ float p[256];
  __shared__ float hh[32];
  p[tid] = pool[b * 256 + tid] * (1.0f / 4096.0f);
  __syncthreads();
  if (tid < 32) {
    float s = b1[tid];
    for (int c = 0; c < 256; ++c) s = fmaf(w1[tid * 256 + c], p[c], s);
    hh[tid] = fmaxf(s, 0.0f);
  }
  __syncthreads();
  float s = b2[tid];
#pragma unroll
  for (int r = 0; r < 32; ++r) s = fmaf(w2[tid * 32 + r], hh[r], s);
  gate[b * 256 + tid] = 1.0f / (1.0f + expf(-s));
}

// ---- fold SE gate into per-batch bf16 output-proj weights ------------------
__global__ __launch_bounds__(256) void scale_w(
    const float* __restrict__ W, const float* __restrict__ gate,
    unsigned short* __restrict__ Wg)
{
  const int b = blockIdx.x, tid = threadIdx.x;
  const float g = gate[b * 256 + tid];
  for (int o = 0; o < 256; ++o)
    Wg[(size_t)b * 65536 + o * 256 + tid] = f2bf(W[o * 256 + tid] * g);
}

// ---- pout (MFMA): out[o][n] = sum_c Wg[o][c]*xout_t[n][c] + bias + res -----
// grid (32 n, 2 o, 8 b). xout_t batch stride db.
__global__ __launch_bounds__(256) void pout_gemm(
    const unsigned short* __restrict__ Wg, const unsigned short* __restrict__ Xt,
    long db, const float* __restrict__ bias, const float* __restrict__ xres,
    float* __restrict__ out)
{
  __shared__ unsigned short As[128 * 64];
  __shared__ unsigned short Bs[128 * 64];
  const int n0 = blockIdx.x * 128, o0 = blockIdx.y * 128, b = blockIdx.z;
  const int tid = threadIdx.x, w = tid >> 6, lane = tid & 63;
  const int wm = (w & 1) * 64, wn = (w >> 1) * 64;
  const int lrow8 = lane >> 3, lcol8 = (lane & 7) * 8;
  f4acc acc[4][4] = {};
  for (int kc = 0; kc < 256; kc += 64) {
    __syncthreads();
#pragma unroll
    for (int j = 0; j < 4; ++j) {
      int i = w * 4 + j;
      GLDS16(Wg + (size_t)b * 65536 + (size_t)(o0 + i * 8 + lrow8) * 256 + kc + lcol8,
             &As[i * 512]);
      GLDS16(Xt + (size_t)b * db + (size_t)(n0 + i * 8 + lrow8) * 256 + kc + lcol8,
             &Bs[i * 512]);
    }
    __syncthreads();
#pragma unroll
    for (int ks = 0; ks < 2; ++ks) {
      bfrag a[4], bb[4];
#pragma unroll
      for (int mt = 0; mt < 4; ++mt)
        a[mt] = *(const bfrag*)&As[(wm + mt * 16 + (lane & 15)) * 64 + ks * 32 + (lane >> 4) * 8];
#pragma unroll
      for (int nt = 0; nt < 4; ++nt)
        bb[nt] = *(const bfrag*)&Bs[(wn + nt * 16 + (lane & 15)) * 64 + ks * 32 + (lane >> 4) * 8];
#pragma unroll
      for (int mt = 0; mt < 4; ++mt)
#pragma unroll
        for (int nt = 0; nt < 4; ++nt)
          acc[mt][nt] = __builtin_amdgcn_mfma_f32_16x16x32_bf16(a[mt], bb[nt], acc[mt][nt], 0, 0, 0);
    }
  }
#pragma unroll
  for (int mt = 0; mt < 4; ++mt) {
    const int or0 = o0 + wm + mt * 16 + (lane >> 4) * 4;
    float bi[4];
#pragma unroll
    for (int r = 0; r < 4; ++r) bi[r] = bias[or0 + r];
#pragma unroll
    for (int nt = 0; nt < 4; ++nt) {
      const int n = n0 + wn + nt * 16 + (lane & 15);
#pragma unroll
      for (int r = 0; r < 4; ++r) {
        const size_t idx = ((size_t)b * 256 + or0 + r) * NPIX + n;
        out[idx] = acc[mt][nt][r] + bi[r] + xres[idx];
      }
    }
  }
}

extern "C" void kernel_launch(void* const* d_in, const int* in_sizes, int n_in,
                              void* d_out, int out_size, void* d_ws, size_t ws_size,
                              hipStream_t stream) {
  const float* x1    = (const float*)d_in[0];
  const float* x2    = (const float*)d_in[1];
  const float* ms_w3 = (const float*)d_in[2];
  const float* ms_b3 = (const float*)d_in[3];
  const float* ms_w5 = (const float*)d_in[4];
  const float* ms_b5 = (const float*)d_in[5];
  const float* ms_w7 = (const float*)d_in[6];
  const float* ms_b7 = (const float*)d_in[7];
  const float* qkv1_w = (const float*)d_in[8];
  const float* qkv1_b = (const float*)d_in[9];
  const float* bn1_g = (const float*)d_in[10];
  const float* bn1_b = (const float*)d_in[11];
  const float* bn1_m = (const float*)d_in[12];
  const float* bn1_v = (const float*)d_in[13];
  const float* qkv2_w = (const float*)d_in[14];
  const float* qkv2_b = (const float*)d_in[15];
  const float* bn2_g = (const float*)d_in[16];
  const float* bn2_b = (const float*)d_in[17];
  const float* bn2_m = (const float*)d_in[18];
  const float* bn2_v = (const float*)d_in[19];
  const float* ca_w1 = (const float*)d_in[20];
  const float* ca_b1 = (const float*)d_in[21];
  const float* ca_w2 = (const float*)d_in[22];
  const float* ca_b2 = (const float*)d_in[23];
  const float* po1_w = (const float*)d_in[24];
  const float* po1_b = (const float*)d_in[25];
  const float* po2_w = (const float*)d_in[26];
  const float* po2_b = (const float*)d_in[27];

  char* ws = (char*)d_ws;
  float* weff  = (float*)(ws + 0);
  float* beff  = (float*)(ws + 51200);
  float* alpha = (float*)(ws + 53248);
  float* beta  = (float*)(ws + 59392);
  float* normsq1 = (float*)(ws + 65536);   // 8*512 fp32
  float* normsq2 = (float*)(ws + 81920);
  float* pool  = (float*)(ws + 98304);     // 2*2048 fp32
  float* gate  = (float*)(ws + 114688);
  unsigned short* W1b = (unsigned short*)(ws + 131072);
  unsigned short* W2b = (unsigned short*)(ws + 524288);
  unsigned short* Wg1 = (unsigned short*)(ws + 917504);
  unsigned short* Wg2 = (unsigned short*)(ws + 1966080);
  unsigned short* attn1 = (unsigned short*)(ws + 3014656);
  unsigned short* attn2 = (unsigned short*)(ws + 3276800);
  float* Sp    = (float*)(ws + 3538944);   // 8*32*4096 fp32
  unsigned short* xf   = (unsigned short*)(ws + 7733248);   // [b][256][4096]
  unsigned short* xf_t = (unsigned short*)(ws + 24510464);  // [b][4096][256]
  unsigned short* qkv1 = (unsigned short*)(ws + 41287680);  // [b][768][4096]
  unsigned short* qkv2 = (unsigned short*)(ws + 91619328);
  // aliased (dead-region reuse):
  unsigned short* v1t   = xf;     // after xf consumed by transpose2
  unsigned short* v2t   = xf_t;   // after xf_t consumed by qkv_gemm2
  unsigned short* xout1 = qkv2;   // per-batch [n][256] in dead q/k chunks, stride 768*4096
  unsigned short* xout2 = qkv1;
  const long QKV_BSTR = 768L * 4096;

  float* outf = (float*)d_out;
  const size_t stream2_off = (size_t)8 * 256 * NPIX;

  prep_kernel<<<1, 256, 0, stream>>>(ms_w3, ms_b3, ms_w5, ms_b5, ms_w7, ms_b7,
                                     qkv1_b, bn1_g, bn1_b, bn1_m, bn1_v,
                                     qkv2_b, bn2_g, bn2_b, bn2_m, bn2_v,
                                     weff, beff, alpha, beta);
  convert_w<<<768, 256, 0, stream>>>(qkv1_w, qkv2_w, W1b, W2b);
  hipMemsetAsync(ws + 65536, 0, 49152, stream);  // normsq1/2 + pool

  // stream 1: conv -> transpose -> qkv GEMM
  ms_conv<<<2048, 256, 0, stream>>>(x1, weff, beff, xf);
  transpose_bf16<<<dim3(64, 4, 8), 256, 0, stream>>>(xf, xf_t, 1048576L, 1048576L);
  qkv_gemm<<<dim3(32, 6, 8), 256, 0, stream>>>(W1b, xf_t, alpha, beta, qkv1, normsq1);
  // stream 2
  ms_conv<<<2048, 256, 0, stream>>>(x2, weff, beff, xf);
  transpose_bf16<<<dim3(64, 4, 8), 256, 0, stream>>>(xf, xf_t, 1048576L, 1048576L);
  qkv_gemm<<<dim3(32, 6, 8), 256, 0, stream>>>(W2b, xf_t, alpha + 768, beta + 768, qkv2, normsq2);

  // attention logits + softmax (attn1: q1.k2, attn2: q2.k1)
  spart_kernel<<<dim3(8, 4, 8), 256, 0, stream>>>(qkv1, qkv2 + 256 * NPIX, Sp);
  softattn<<<32, 256, 0, stream>>>(Sp, normsq1, normsq2, attn1);
  spart_kernel<<<dim3(8, 4, 8), 256, 0, stream>>>(qkv2, qkv1 + 256 * NPIX, Sp);
  softattn<<<32, 256, 0, stream>>>(Sp, normsq2, normsq1, attn2);

  // v transposes (into dead xf / xf_t)
  transpose_bf16<<<dim3(64, 4, 8), 256, 0, stream>>>(qkv1 + 512 * NPIX, v1t, 3145728L, 1048576L);
  transpose_bf16<<<dim3(64, 4, 8), 256, 0, stream>>>(qkv2 + 512 * NPIX, v2t, 3145728L, 1048576L);

  // xout_t = v_t . attn^T  (+ SE pooling)
  av_kernel<<<dim3(16, 4, 8), 256, 0, stream>>>(v1t, attn1, xout1, QKV_BSTR, pool);
  av_kernel<<<dim3(16, 4, 8), 256, 0, stream>>>(v2t, attn2, xout2, QKV_BSTR, pool + 2048);

  // SE gates, fold into output-proj weights
  segate<<<8, 256, 0, stream>>>(pool, ca_w1, ca_b1, ca_w2, ca_b2, gate);
  segate<<<8, 256, 0, stream>>>(pool + 2048, ca_w1, ca_b1, ca_w2, ca_b2, gate + 2048);
  scale_w<<<8, 256, 0, stream>>>(po1_w, gate, Wg1);
  scale_w<<<8, 256, 0, stream>>>(po2_w, gate + 2048, Wg2);

  // final projection + bias + residual
  pout_gemm<<<dim3(32, 2, 8), 256, 0, stream>>>(Wg1, xout1, QKV_BSTR, po1_b, x1, outf);
  pout_gemm<<<dim3(32, 2, 8), 256, 0, stream>>>(Wg2, xout2, QKV_BSTR, po2_b, x2,
                                                outf + stream2_off);
}

// Round 4
// 521.196 us; speedup vs baseline: 1.7187x; 1.0672x over previous
//
#include <hip/hip_runtime.h>
#include <hip/hip_bf16.h>

// ---------------------------------------------------------------------------
// SCFA fused pipeline, bf16 MFMA GEMMs, fp32 epilogues.
// B=8, C=256, N=4096, NH=4, HD=64.
// R4: XOR-swizzled LDS (kills 16-way bank conflicts on ds_read_b128),
//     swapped MFMA operand roles (acc regs = 4 consecutive output cols ->
//     packed ushort4/float4 stores), sigmoid-form fast gelu.
// ---------------------------------------------------------------------------

#define NPIX 4096

typedef __attribute__((ext_vector_type(8))) short bfrag;   // 8 bf16 (4 VGPR)
typedef __attribute__((ext_vector_type(4))) float f4acc;   // 4 fp32 acc

#define GLDS16(g, l) __builtin_amdgcn_global_load_lds( \
    (const __attribute__((address_space(1))) unsigned int*)(g), \
    (__attribute__((address_space(3))) unsigned int*)(l), 16, 0, 0)

__device__ __forceinline__ float bf2f(unsigned short h) {
  return __uint_as_float(((unsigned)h) << 16);
}
__device__ __forceinline__ unsigned short f2bf(float f) {
  unsigned u = __float_as_uint(f);
  unsigned r = (u + 0x7FFFu + ((u >> 16) & 1u)) >> 16;
  return (unsigned short)r;
}
// tanh-form gelu == x * sigmoid(1.5957691x + 0.07135481x^3); max err ~3e-3
__device__ __forceinline__ float gelu_f(float x) {
  float z = x * (1.5957691216f + 0.0713548163f * x * x);
  return x / (1.0f + __expf(-z));
}

// ---- prep: fold depthwise kernels, fold BN+bias ----------------------------
__global__ __launch_bounds__(256) void prep_kernel(
    const float* __restrict__ w3, const float* __restrict__ b3,
    const float* __restrict__ w5, const float* __restrict__ b5,
    const float* __restrict__ w7, const float* __restrict__ b7,
    const float* __restrict__ qb1, const float* __restrict__ g1,
    const float* __restrict__ be1, const float* __restrict__ m1,
    const float* __restrict__ v1,
    const float* __restrict__ qb2, const float* __restrict__ g2,
    const float* __restrict__ be2, const float* __restrict__ m2,
    const float* __restrict__ v2,
    float* __restrict__ weff, float* __restrict__ beff,
    float* __restrict__ alpha, float* __restrict__ beta)
{
  const int c = threadIdx.x;
  for (int ky = 0; ky < 7; ++ky)
    for (int kx = 0; kx < 7; ++kx) {
      float w = w7[c * 49 + ky * 7 + kx];
      if (ky >= 1 && ky <= 5 && kx >= 1 && kx <= 5)
        w += w5[c * 25 + (ky - 1) * 5 + (kx - 1)];
      if (ky >= 2 && ky <= 4 && kx >= 2 && kx <= 4)
        w += w3[c * 9 + (ky - 2) * 3 + (kx - 2)];
      weff[c * 49 + ky * 7 + kx] = w * (1.0f / 3.0f);
    }
  beff[c] = (b3[c] + b5[c] + b7[c]) * (1.0f / 3.0f);
  for (int o = c; o < 768; o += 256) {
    float inv1 = g1[o] / sqrtf(v1[o] + 1e-5f);
    alpha[o] = inv1;
    beta[o]  = qb1[o] * inv1 + be1[o] - m1[o] * inv1;
    float inv2 = g2[o] / sqrtf(v2[o] + 1e-5f);
    alpha[768 + o] = inv2;
    beta[768 + o]  = qb2[o] * inv2 + be2[o] - m2[o] * inv2;
  }
}

// ---- convert qkv weights fp32 -> bf16 (both streams) -----------------------
__global__ __launch_bounds__(256) void convert_w(
    const float* __restrict__ s1, const float* __restrict__ s2,
    unsigned short* __restrict__ d1, unsigned short* __restrict__ d2)
{
  int idx = blockIdx.x * 256 + threadIdx.x;
  d1[idx] = f2bf(s1[idx]);
  d2[idx] = f2bf(s2[idx]);
}

// ---- fused multi-scale depthwise conv -> bf16 [c][n] -----------------------
__global__ __launch_bounds__(256) void ms_conv(
    const float* __restrict__ x, const float* __restrict__ weff,
    const float* __restrict__ beff, unsigned short* __restrict__ xf)
{
  __shared__ float tile[70][76];
  const int bc = blockIdx.x;      // b*256 + c
  const int c = bc & 255;
  const int tid = threadIdx.x;
  const float* src = x + (size_t)bc * NPIX;
  float wreg[49];
#pragma unroll
  for (int i = 0; i < 49; ++i) wreg[i] = weff[c * 49 + i];
  const float bias = beff[c];
  for (int idx = tid; idx < 70 * 76; idx += 256) {
    int ry = idx / 76, cx = idx - ry * 76;
    int gy = ry - 3, gx = cx - 4;
    float v = 0.0f;
    if ((unsigned)gy < 64u && (unsigned)gx < 64u) v = src[gy * 64 + gx];
    tile[ry][cx] = v;
  }
  __syncthreads();
  const int x0 = (tid & 15) * 4;
  const int y0 = (tid >> 4) * 4;
  float acc[4][4];
#pragma unroll
  for (int yo = 0; yo < 4; ++yo)
#pragma unroll
    for (int xo = 0; xo < 4; ++xo) acc[yo][xo] = bias;
#pragma unroll
  for (int r = 0; r < 10; ++r) {
    float seg[12];
    *(float4*)&seg[0] = *(const float4*)&tile[y0 + r][x0];
    *(float4*)&seg[4] = *(const float4*)&tile[y0 + r][x0 + 4];
    *(float4*)&seg[8] = *(const float4*)&tile[y0 + r][x0 + 8];
    const int yolo = (r >= 6) ? (r - 6) : 0;
    const int yohi = (r < 3) ? r : 3;
#pragma unroll
    for (int yo = 0; yo < 4; ++yo) {
      if (yo < yolo || yo > yohi) continue;
      const int ky = r - yo;
#pragma unroll
      for (int kx = 0; kx < 7; ++kx) {
        const float w = wreg[ky * 7 + kx];
#pragma unroll
        for (int xo = 0; xo < 4; ++xo)
          acc[yo][xo] = fmaf(w, seg[1 + xo + kx], acc[yo][xo]);
      }
    }
  }
  unsigned short* dst = xf + (size_t)bc * NPIX;
#pragma unroll
  for (int yo = 0; yo < 4; ++yo) {
    ushort4 u;
    u.x = f2bf(acc[yo][0]); u.y = f2bf(acc[yo][1]);
    u.z = f2bf(acc[yo][2]); u.w = f2bf(acc[yo][3]);
    *(ushort4*)&dst[(y0 + yo) * 64 + x0] = u;
  }
}

// ---- bf16 [R rows][4096] -> [4096][256] tile transpose ---------------------
__global__ __launch_bounds__(256) void transpose_bf16(
    const unsigned short* __restrict__ src, unsigned short* __restrict__ dst,
    long sb, long db)
{
  __shared__ unsigned short T[64][72];
  const int n0 = blockIdx.x * 64, c0 = blockIdx.y * 64, b = blockIdx.z;
  const int t = threadIdx.x;
  const int rhi = t >> 4, c4 = (t & 15) * 4;
#pragma unroll
  for (int rr = 0; rr < 4; ++rr) {
    int row = rr * 16 + rhi;
    ushort4 u = *(const ushort4*)&src[(size_t)b * sb + (size_t)(c0 + row) * NPIX + n0 + c4];
    T[row][c4 + 0] = u.x; T[row][c4 + 1] = u.y;
    T[row][c4 + 2] = u.z; T[row][c4 + 3] = u.w;
  }
  __syncthreads();
#pragma unroll
  for (int rr = 0; rr < 4; ++rr) {
    int nrow = rr * 16 + rhi;
    ushort4 u;
    u.x = T[c4 + 0][nrow]; u.y = T[c4 + 1][nrow];
    u.z = T[c4 + 2][nrow]; u.w = T[c4 + 3][nrow];
    *(ushort4*)&dst[(size_t)b * db + (size_t)(n0 + nrow) * 256 + c0 + c4] = u;
  }
}

// ---- qkv 1x1 GEMM (MFMA): D[n][o], A=Xt(n rows), B=W(o rows) ---------------
// LDS swizzle: slot g -> g ^ (row & 7). Epilogue: BN+gelu, ushort4 stores to
// qkv[o][n] (regs = 4 consecutive n), fused q/k row-sumsq atomics.
__global__ __launch_bounds__(256) void qkv_gemm(
    const unsigned short* __restrict__ Wb, const unsigned short* __restrict__ Xt,
    const float* __restrict__ alpha, const float* __restrict__ beta,
    unsigned short* __restrict__ qkv, float* __restrict__ normsq)
{
  __shared__ unsigned short As[128 * 64];  // W tile (o rows)
  __shared__ unsigned short Bs[128 * 64];  // Xt tile (n rows)
  const int n0 = blockIdx.x * 128, o0 = blockIdx.y * 128, b = blockIdx.z;
  const int tid = threadIdx.x, w = tid >> 6, lane = tid & 63;
  const int wm = (w & 1) * 64;   // n wave offset
  const int wn = (w >> 1) * 64;  // o wave offset
  const int lrow8 = lane >> 3;
  const int lcolsw = ((lane & 7) ^ lrow8) * 8;  // swizzled source column
  const int fslot = lane & 7;                    // read-side row&7
  f4acc acc[4][4] = {};
  for (int kc = 0; kc < 256; kc += 64) {
    __syncthreads();
#pragma unroll
    for (int j = 0; j < 4; ++j) {
      int i = w * 4 + j;
      GLDS16(Wb + (size_t)(o0 + i * 8 + lrow8) * 256 + kc + lcolsw, &As[i * 512]);
      GLDS16(Xt + (size_t)b * 1048576 + (size_t)(n0 + i * 8 + lrow8) * 256 + kc + lcolsw,
             &Bs[i * 512]);
    }
    __syncthreads();
#pragma unroll
    for (int ks = 0; ks < 2; ++ks) {
      const int slot = ((ks * 4 + (lane >> 4)) ^ fslot) * 8;
      bfrag a[4], bb[4];
#pragma unroll
      for (int mt = 0; mt < 4; ++mt)   // A = Xt rows (n)
        a[mt] = *(const bfrag*)&Bs[(wm + mt * 16 + (lane & 15)) * 64 + slot];
#pragma unroll
      for (int nt = 0; nt < 4; ++nt)   // B = W rows (o)
        bb[nt] = *(const bfrag*)&As[(wn + nt * 16 + (lane & 15)) * 64 + slot];
#pragma unroll
      for (int mt = 0; mt < 4; ++mt)
#pragma unroll
        for (int nt = 0; nt < 4; ++nt)
          acc[mt][nt] = __builtin_amdgcn_mfma_f32_16x16x32_bf16(a[mt], bb[nt], acc[mt][nt], 0, 0, 0);
    }
  }
  // epilogue: D rows = n (regs), cols = o (lane&15)
#pragma unroll
  for (int nt = 0; nt < 4; ++nt) {
    const int o = o0 + wn + nt * 16 + (lane & 15);
    const float al = alpha[o], be = beta[o];
    unsigned short* orow = qkv + ((size_t)b * 768 + o) * NPIX;
    float sq = 0.0f;
#pragma unroll
    for (int mt = 0; mt < 4; ++mt) {
      const int n = n0 + wm + mt * 16 + (lane >> 4) * 4;
      float v0 = gelu_f(acc[mt][nt][0] * al + be);
      float v1 = gelu_f(acc[mt][nt][1] * al + be);
      float v2 = gelu_f(acc[mt][nt][2] * al + be);
      float v3 = gelu_f(acc[mt][nt][3] * al + be);
      ushort4 u;
      u.x = f2bf(v0); u.y = f2bf(v1); u.z = f2bf(v2); u.w = f2bf(v3);
      *(ushort4*)&orow[n] = u;
      sq += v0 * v0 + v1 * v1 + v2 * v2 + v3 * v3;
    }
    if (o0 + wn + nt * 16 < 512) {  // q or k rows
      sq += __shfl_xor(sq, 16);
      sq += __shfl_xor(sq, 32);
      if (lane < 16) atomicAdd(&normsq[b * 512 + o], sq);
    }
  }
}

// ---- spart (MFMA): Sp[c][d] += sum_n q[c][n]*k[d][n]; A=k(d), B=q(c) -------
// grid (8 chunks of 512 n, 4 h, 8 b). 128-el rows, swizzle mask &15.
__global__ __launch_bounds__(256) void spart_kernel(
    const unsigned short* __restrict__ qs, const unsigned short* __restrict__ ks,
    float* __restrict__ Sp)
{
  __shared__ unsigned short Qs[64 * 128];
  __shared__ unsigned short Ks[64 * 128];
  const int ck = blockIdx.x, h = blockIdx.y, b = blockIdx.z;
  const int tid = threadIdx.x, w = tid >> 6, lane = tid & 63;
  const int lrow16 = lane >> 4;
  const size_t qbase = ((size_t)b * 768 + h * 64) * NPIX;
  f4acc acc[4] = {};   // mt over d tiles
  for (int it = 0; it < 4; ++it) {
    const int noff = ck * 512 + it * 128;
    __syncthreads();
#pragma unroll
    for (int j = 0; j < 4; ++j) {
      int i = w * 4 + j;
      int row = i * 4 + lrow16;
      int colsw = (((lane & 15) ^ (row & 15))) * 8;
      GLDS16(qs + qbase + (size_t)row * NPIX + noff + colsw, &Qs[i * 512]);
      GLDS16(ks + qbase + (size_t)row * NPIX + noff + colsw, &Ks[i * 512]);
    }
    __syncthreads();
#pragma unroll
    for (int kk = 0; kk < 4; ++kk) {
      const int slot = (((kk * 4 + (lane >> 4)) ^ (lane & 15))) * 8;
      bfrag bq = *(const bfrag*)&Qs[(w * 16 + (lane & 15)) * 128 + slot];  // B = q (c)
#pragma unroll
      for (int mt = 0; mt < 4; ++mt) {
        bfrag ak = *(const bfrag*)&Ks[(mt * 16 + (lane & 15)) * 128 + slot];  // A = k (d)
        acc[mt] = __builtin_amdgcn_mfma_f32_16x16x32_bf16(ak, bq, acc[mt], 0, 0, 0);
      }
    }
  }
  // D rows = d (regs), cols = c (lane&15); c covered by wave w: w*16..+15
  float* dst = Sp + ((size_t)(ck * 32) + b * 4 + h) * 4096;
  const int c = w * 16 + (lane & 15);
#pragma unroll
  for (int mt = 0; mt < 4; ++mt)
    *(float4*)&dst[c * 64 + mt * 16 + (lane >> 4) * 4] = *(float4*)&acc[mt];
}

// ---- reduce partials, scale by inv norms * temp, softmax, write bf16 -------
__global__ __launch_bounds__(256) void softattn(
    const float* __restrict__ Sp, const float* __restrict__ nsq,
    const float* __restrict__ nsk, unsigned short* __restrict__ attn)
{
  const int bh = blockIdx.x;
  const int b = bh >> 2, h = bh & 3;
  const int wv = threadIdx.x >> 6, lane = threadIdx.x & 63;
  const float ikd = 1.0f / fmaxf(sqrtf(nsk[b * 512 + 256 + h * 64 + lane]), 1e-12f);
  for (int c = wv; c < 64; c += 4) {
    float s = 0.0f;
#pragma unroll
    for (int ch = 0; ch < 8; ++ch)
      s += Sp[((size_t)(ch * 32) + bh) * 4096 + c * 64 + lane];
    const float iq = 1.0f / fmaxf(sqrtf(nsq[b * 512 + h * 64 + c]), 1e-12f);
    float z = s * 0.125f * iq * ikd;
    float m = z;
#pragma unroll
    for (int off = 32; off > 0; off >>= 1) m = fmaxf(m, __shfl_xor(m, off));
    float e = expf(z - m);
    float sum = e;
#pragma unroll
    for (int off = 32; off > 0; off >>= 1) sum += __shfl_xor(sum, off);
    attn[(size_t)bh * 4096 + c * 64 + lane] = f2bf(e / sum);
  }
}

// ---- av (MFMA): xout_t[n'][c] = sum_d attn[c][d]*v_t[n'][d] ----------------
// A = attn (c rows), B = vt (n' rows) -> regs = 4 consecutive c at fixed n'.
// grid (16 chunks of 256 n', 4 h, 8 b).
__global__ __launch_bounds__(256) void av_kernel(
    const unsigned short* __restrict__ vt, const unsigned short* __restrict__ attn,
    unsigned short* __restrict__ xout, long db, float* __restrict__ pool)
{
  __shared__ unsigned short Vs[256 * 64];
  __shared__ unsigned short At[64 * 64];
  const int n0 = blockIdx.x * 256, h = blockIdx.y, b = blockIdx.z;
  const int tid = threadIdx.x, w = tid >> 6, lane = tid & 63;
  const int lrow8 = lane >> 3;
  const int lcolsw = ((lane & 7) ^ lrow8) * 8;
  const int bh = b * 4 + h;
#pragma unroll
  for (int j = 0; j < 8; ++j) {
    int i = w * 8 + j;
    GLDS16(vt + ((size_t)b * 1048576 + (size_t)(n0 + i * 8 + lrow8) * 256) + h * 64 + lcolsw,
           &Vs[i * 512]);
  }
#pragma unroll
  for (int j = 0; j < 2; ++j) {
    int i = w * 2 + j;
    GLDS16(attn + (size_t)bh * 4096 + (size_t)(i * 8 + lrow8) * 64 + lcolsw, &At[i * 512]);
  }
  __syncthreads();
  f4acc acc[4][4] = {};   // [mt = c tile][nt = n' tile]
#pragma unroll
  for (int ks = 0; ks < 2; ++ks) {
    const int slot = ((ks * 4 + (lane >> 4)) ^ (lane & 7)) * 8;
    bfrag a[4], bb[4];
#pragma unroll
    for (int mt = 0; mt < 4; ++mt)    // A = attn rows (c)
      a[mt] = *(const bfrag*)&At[(mt * 16 + (lane & 15)) * 64 + slot];
#pragma unroll
    for (int nt = 0; nt < 4; ++nt)    // B = vt rows (n')
      bb[nt] = *(const bfrag*)&Vs[(w * 64 + nt * 16 + (lane & 15)) * 64 + slot];
#pragma unroll
    for (int mt = 0; mt < 4; ++mt)
#pragma unroll
      for (int nt = 0; nt < 4; ++nt)
        acc[mt][nt] = __builtin_amdgcn_mfma_f32_16x16x32_bf16(a[mt], bb[nt], acc[mt][nt], 0, 0, 0);
  }
  // D rows = c (regs), cols = n' (lane&15)
#pragma unroll
  for (int mt = 0; mt < 4; ++mt) {
    const int c = mt * 16 + (lane >> 4) * 4;
    float s0 = 0.0f, s1 = 0.0f, s2 = 0.0f, s3 = 0.0f;
#pragma unroll
    for (int nt = 0; nt < 4; ++nt) {
      const int np = n0 + w * 64 + nt * 16 + (lane & 15);
      ushort4 u;
      u.x = f2bf(acc[mt][nt][0]); u.y = f2bf(acc[mt][nt][1]);
      u.z = f2bf(acc[mt][nt][2]); u.w = f2bf(acc[mt][nt][3]);
      *(ushort4*)&xout[(size_t)b * db + (size_t)np * 256 + h * 64 + c] = u;
      s0 += acc[mt][nt][0]; s1 += acc[mt][nt][1];
      s2 += acc[mt][nt][2]; s3 += acc[mt][nt][3];
    }
    // reduce over n' (lane&15) for fixed c
    s0 += __shfl_xor(s0, 1); s0 += __shfl_xor(s0, 2); s0 += __shfl_xor(s0, 4); s0 += __shfl_xor(s0, 8);
    s1 += __shfl_xor(s1, 1); s1 += __shfl_xor(s1, 2); s1 += __shfl_xor(s1, 4); s1 += __shfl_xor(s1, 8);
    s2 += __shfl_xor(s2, 1); s2 += __shfl_xor(s2, 2); s2 += __shfl_xor(s2, 4); s2 += __shfl_xor(s2, 8);
    s3 += __shfl_xor(s3, 1); s3 += __shfl_xor(s3, 2); s3 += __shfl_xor(s3, 4); s3 += __shfl_xor(s3, 8);
    if ((lane & 15) == 0) {
      atomicAdd(&pool[b * 256 + h * 64 + c + 0], s0);
      atomicAdd(&pool[b * 256 + h * 64 + c + 1], s1);
      atomicAdd(&pool[b * 256 + h * 64 + c + 2], s2);
      atomicAdd(&pool[b * 256 + h * 64 + c + 3], s3);
    }
  }
}

// ---- SE gate MLP ------------------------------------------------------------
__global__ __launch_bounds__(256) void segate(
    const float* __restrict__ pool, const float* __restrict__ w1,
    const float* __restrict__ b1, const float* __restrict__ w2,
    const float* __restrict__ b2, float* __restrict__ gate)
{
  const int b = blockIdx.x;
  const int tid = threadIdx.x;
  __shared__ float p[256];
  __shared__ float hh[32];
  p[tid] = pool[b * 256 + tid] * (1.0f / 4096.0f);
  __syncthreads();
  if (tid < 32) {
    float s = b1[tid];
    for (int c = 0; c < 256; ++c) s = fmaf(w1[tid * 256 + c], p[c], s);
    hh[tid] = fmaxf(s, 0.0f);
  }
  __syncthreads();
  float s = b2[tid];
#pragma unroll
  for (int r = 0; r < 32; ++r) s = fmaf(w2[tid * 32 + r], hh[r], s);
  gate[b * 256 + tid] = 1.0f / (1.0f + expf(-s));
}

// ---- fold SE gate into per-batch bf16 output-proj weights ------------------
__global__ __launch_bounds__(256) void scale_w(
    const float* __restrict__ W, const float* __restrict__ gate,
    unsigned short* __restrict__ Wg)
{
  const int b = blockIdx.x, tid = threadIdx.x;
  const float g = gate[b * 256 + tid];
  for (int o = 0; o < 256; ++o)
    Wg[(size_t)b * 65536 + o * 256 + tid] = f2bf(W[o * 256 + tid] * g);
}

// ---- pout (MFMA): out[o][n] = sum_c Wg[o][c]*xout_t[n][c] + bias + res -----
// A = Xt (n rows), B = Wg (o rows) -> regs = 4 consecutive n at fixed o.
__global__ __launch_bounds__(256) void pout_gemm(
    const unsigned short* __restrict__ Wg, const unsigned short* __restrict__ Xt,
    long db, const float* __restrict__ bias, const float* __restrict__ xres,
    float* __restrict__ out)
{
  __shared__ unsigned short As[128 * 64];  // Wg (o rows)
  __shared__ unsigned short Bs[128 * 64];  // Xt (n rows)
  const int n0 = blockIdx.x * 128, o0 = blockIdx.y * 128, b = blockIdx.z;
  const int tid = threadIdx.x, w = tid >> 6, lane = tid & 63;
  const int wm = (w & 1) * 64;   // n
  const int wn = (w >> 1) * 64;  // o
  const int lrow8 = lane >> 3;
  const int lcolsw = ((lane & 7) ^ lrow8) * 8;
  const int fslot = lane & 7;
  f4acc acc[4][4] = {};
  for (int kc = 0; kc < 256; kc += 64) {
    __syncthreads();
#pragma unroll
    for (int j = 0; j < 4; ++j) {
      int i = w * 4 + j;
      GLDS16(Wg + (size_t)b * 65536 + (size_t)(o0 + i * 8 + lrow8) * 256 + kc + lcolsw,
             &As[i * 512]);
      GLDS16(Xt + (size_t)b * db + (size_t)(n0 + i * 8 + lrow8) * 256 + kc + lcolsw,
             &Bs[i * 512]);
    }
    __syncthreads();
#pragma unroll
    for (int ks = 0; ks < 2; ++ks) {
      const int slot = ((ks * 4 + (lane >> 4)) ^ fslot) * 8;
      bfrag a[4], bb[4];
#pragma unroll
      for (int mt = 0; mt < 4; ++mt)   // A = Xt rows (n)
        a[mt] = *(const bfrag*)&Bs[(wm + mt * 16 + (lane & 15)) * 64 + slot];
#pragma unroll
      for (int nt = 0; nt < 4; ++nt)   // B = Wg rows (o)
        bb[nt] = *(const bfrag*)&As[(wn + nt * 16 + (lane & 15)) * 64 + slot];
#pragma unroll
      for (int mt = 0; mt < 4; ++mt)
#pragma unroll
        for (int nt = 0; nt < 4; ++nt)
          acc[mt][nt] = __builtin_amdgcn_mfma_f32_16x16x32_bf16(a[mt], bb[nt], acc[mt][nt], 0, 0, 0);
    }
  }
#pragma unroll
  for (int nt = 0; nt < 4; ++nt) {
    const int o = o0 + wn + nt * 16 + (lane & 15);
    const float bi = bias[o];
    const float* res = xres + ((size_t)b * 256 + o) * NPIX;
    float* orow = out + ((size_t)b * 256 + o) * NPIX;
#pragma unroll
    for (int mt = 0; mt < 4; ++mt) {
      const int n = n0 + wm + mt * 16 + (lane >> 4) * 4;
      float4 r4 = *(const float4*)&res[n];
      float4 ov;
      ov.x = acc[mt][nt][0] + bi + r4.x;
      ov.y = acc[mt][nt][1] + bi + r4.y;
      ov.z = acc[mt][nt][2] + bi + r4.z;
      ov.w = acc[mt][nt][3] + bi + r4.w;
      *(float4*)&orow[n] = ov;
    }
  }
}

extern "C" void kernel_launch(void* const* d_in, const int* in_sizes, int n_in,
                              void* d_out, int out_size, void* d_ws, size_t ws_size,
                              hipStream_t stream) {
  const float* x1    = (const float*)d_in[0];
  const float* x2    = (const float*)d_in[1];
  const float* ms_w3 = (const float*)d_in[2];
  const float* ms_b3 = (const float*)d_in[3];
  const float* ms_w5 = (const float*)d_in[4];
  const float* ms_b5 = (const float*)d_in[5];
  const float* ms_w7 = (const float*)d_in[6];
  const float* ms_b7 = (const float*)d_in[7];
  const float* qkv1_w = (const float*)d_in[8];
  const float* qkv1_b = (const float*)d_in[9];
  const float* bn1_g = (const float*)d_in[10];
  const float* bn1_b = (const float*)d_in[11];
  const float* bn1_m = (const float*)d_in[12];
  const float* bn1_v = (const float*)d_in[13];
  const float* qkv2_w = (const float*)d_in[14];
  const float* qkv2_b = (const float*)d_in[15];
  const float* bn2_g = (const float*)d_in[16];
  const float* bn2_b = (const float*)d_in[17];
  const float* bn2_m = (const float*)d_in[18];
  const float* bn2_v = (const float*)d_in[19];
  const float* ca_w1 = (const float*)d_in[20];
  const float* ca_b1 = (const float*)d_in[21];
  const float* ca_w2 = (const float*)d_in[22];
  const float* ca_b2 = (const float*)d_in[23];
  const float* po1_w = (const float*)d_in[24];
  const float* po1_b = (const float*)d_in[25];
  const float* po2_w = (const float*)d_in[26];
  const float* po2_b = (const float*)d_in[27];

  char* ws = (char*)d_ws;
  float* weff  = (float*)(ws + 0);
  float* beff  = (float*)(ws + 51200);
  float* alpha = (float*)(ws + 53248);
  float* beta  = (float*)(ws + 59392);
  float* normsq1 = (float*)(ws + 65536);   // 8*512 fp32
  float* normsq2 = (float*)(ws + 81920);
  float* pool  = (float*)(ws + 98304);     // 2*2048 fp32
  float* gate  = (float*)(ws + 114688);
  unsigned short* W1b = (unsigned short*)(ws + 131072);
  unsigned short* W2b = (unsigned short*)(ws + 524288);
  unsigned short* Wg1 = (unsigned short*)(ws + 917504);
  unsigned short* Wg2 = (unsigned short*)(ws + 1966080);
  unsigned short* attn1 = (unsigned short*)(ws + 3014656);
  unsigned short* attn2 = (unsigned short*)(ws + 3276800);
  float* Sp    = (float*)(ws + 3538944);   // 8*32*4096 fp32
  unsigned short* xf   = (unsigned short*)(ws + 7733248);   // [b][256][4096]
  unsigned short* xf_t = (unsigned short*)(ws + 24510464);  // [b][4096][256]
  unsigned short* qkv1 = (unsigned short*)(ws + 41287680);  // [b][768][4096]
  unsigned short* qkv2 = (unsigned short*)(ws + 91619328);
  unsigned short* v1t   = xf;
  unsigned short* v2t   = xf_t;
  unsigned short* xout1 = qkv2;   // per-batch [n][256] in dead q/k chunks
  unsigned short* xout2 = qkv1;
  const long QKV_BSTR = 768L * 4096;

  float* outf = (float*)d_out;
  const size_t stream2_off = (size_t)8 * 256 * NPIX;

  prep_kernel<<<1, 256, 0, stream>>>(ms_w3, ms_b3, ms_w5, ms_b5, ms_w7, ms_b7,
                                     qkv1_b, bn1_g, bn1_b, bn1_m, bn1_v,
                                     qkv2_b, bn2_g, bn2_b, bn2_m, bn2_v,
                                     weff, beff, alpha, beta);
  convert_w<<<768, 256, 0, stream>>>(qkv1_w, qkv2_w, W1b, W2b);
  hipMemsetAsync(ws + 65536, 0, 49152, stream);  // normsq1/2 + pool

  ms_conv<<<2048, 256, 0, stream>>>(x1, weff, beff, xf);
  transpose_bf16<<<dim3(64, 4, 8), 256, 0, stream>>>(xf, xf_t, 1048576L, 1048576L);
  qkv_gemm<<<dim3(32, 6, 8), 256, 0, stream>>>(W1b, xf_t, alpha, beta, qkv1, normsq1);
  ms_conv<<<2048, 256, 0, stream>>>(x2, weff, beff, xf);
  transpose_bf16<<<dim3(64, 4, 8), 256, 0, stream>>>(xf, xf_t, 1048576L, 1048576L);
  qkv_gemm<<<dim3(32, 6, 8), 256, 0, stream>>>(W2b, xf_t, alpha + 768, beta + 768, qkv2, normsq2);

  spart_kernel<<<dim3(8, 4, 8), 256, 0, stream>>>(qkv1, qkv2 + 256 * NPIX, Sp);
  softattn<<<32, 256, 0, stream>>>(Sp, normsq1, normsq2, attn1);
  spart_kernel<<<dim3(8, 4, 8), 256, 0, stream>>>(qkv2, qkv1 + 256 * NPIX, Sp);
  softattn<<<32, 256, 0, stream>>>(Sp, normsq2, normsq1, attn2);

  transpose_bf16<<<dim3(64, 4, 8), 256, 0, stream>>>(qkv1 + 512 * NPIX, v1t, 3145728L, 1048576L);
  transpose_bf16<<<dim3(64, 4, 8), 256, 0, stream>>>(qkv2 + 512 * NPIX, v2t, 3145728L, 1048576L);

  av_kernel<<<dim3(16, 4, 8), 256, 0, stream>>>(v1t, attn1, xout1, QKV_BSTR, pool);
  av_kernel<<<dim3(16, 4, 8), 256, 0, stream>>>(v2t, attn2, xout2, QKV_BSTR, pool + 2048);

  segate<<<8, 256, 0, stream>>>(pool, ca_w1, ca_b1, ca_w2, ca_b2, gate);
  segate<<<8, 256, 0, stream>>>(pool + 2048, ca_w1, ca_b1, ca_w2, ca_b2, gate + 2048);
  scale_w<<<8, 256, 0, stream>>>(po1_w, gate, Wg1);
  scale_w<<<8, 256, 0, stream>>>(po2_w, gate + 2048, Wg2);

  pout_gemm<<<dim3(32, 2, 8), 256, 0, stream>>>(Wg1, xout1, QKV_BSTR, po1_b, x1, outf);
  pout_gemm<<<dim3(32, 2, 8), 256, 0, stream>>>(Wg2, xout2, QKV_BSTR, po2_b, x2,
                                                outf + stream2_off);
}